// Round 2
// baseline (515.971 us; speedup 1.0000x reference)
//
#include <hip/hip_runtime.h>

// ---------------------------------------------------------------------------
// MHA: out = ((softmax(mask((XqWq+bq)(XkWk+bk)^T/8)) (XvWv+bv)) Wo + bo)^T
// B=2, S=2048, HID=1024, H=16, Dh=64.  All fp32 in/out.
//
// Strategy: 3-term bf16 hi/lo split MFMA (a_h*b_h + a_h*b_l + a_l*b_h) for
// fp32-accurate matmuls on the 2.5PF bf16 matrix pipe. All operands are
// pre-packed into MFMA fragment-native layout [o16][k8][16][8] (hi/lo ushort
// arrays) so every fragment load is a lane-contiguous coalesced 16B load.
// ---------------------------------------------------------------------------

typedef unsigned short ushort_t;
typedef __attribute__((ext_vector_type(8))) short short8;
typedef __attribute__((ext_vector_type(4))) float f32x4;

#define S_LEN 2048
#define HID 1024
#define NH 16
#define DH 64
#define MTOT 4096            // B*S rows
#define KB 128               // HID/8 k8-blocks
#define PERHEAD 131072       // per-(b,h) packed elems (S*64 = 2048*64)

// RNE fp32 -> bf16 split: x ~= hi + lo (both bf16), |x-hi-lo| <~ 2^-17 |x|
__device__ __forceinline__ void bsplit(float x, ushort_t& h, ushort_t& l) {
  unsigned u = __float_as_uint(x);
  unsigned hr = (u + 0x7fffu + ((u >> 16) & 1u)) >> 16;
  h = (ushort_t)hr;
  float hf = __uint_as_float(hr << 16);
  float r = x - hf;  // exact (Sterbenz-adjacent)
  unsigned u2 = __float_as_uint(r);
  l = (ushort_t)((u2 + 0x7fffu + ((u2 >> 16) & 1u)) >> 16);
}

// ---------------------------------------------------------------------------
// pack_mat: fp32 row-major -> packed hi/lo fragment layout [o16][k8][16][8].
// bmode 0: A-side (src[m][k], 16-dim = m rows). coalesced float4 reads.
// bmode 1: B-side (src[k][n], 16-dim = n cols). per-j coalesced reads.
// dst flat index = tid*8+j with tid=(o16*KB+k8)*16+r  (writes fully coalesced)
// ---------------------------------------------------------------------------
__global__ __launch_bounds__(256) void pack_mat(const float* __restrict__ src,
                                                ushort_t* __restrict__ hi,
                                                ushort_t* __restrict__ lo,
                                                int bmode) {
  int tid = blockIdx.x * 256 + threadIdx.x;
  int r = tid & 15;
  int k8 = (tid >> 4) & (KB - 1);
  int o16 = tid >> 11;
  float v[8];
  if (bmode == 0) {
    const float* s = src + (size_t)(o16 * 16 + r) * HID + k8 * 8;
    const f32x4 f0 = *(const f32x4*)s;
    const f32x4 f1 = *(const f32x4*)(s + 4);
#pragma unroll
    for (int j = 0; j < 4; ++j) { v[j] = f0[j]; v[4 + j] = f1[j]; }
  } else {
#pragma unroll
    for (int j = 0; j < 8; ++j)
      v[j] = src[(size_t)(k8 * 8 + j) * HID + o16 * 16 + r];
  }
  short8 H, L;
#pragma unroll
  for (int j = 0; j < 8; ++j) {
    ushort_t h, l;
    bsplit(v[j], h, l);
    H[j] = (short)h;
    L[j] = (short)l;
  }
  *(short8*)(hi + (size_t)tid * 8) = H;
  *(short8*)(lo + (size_t)tid * 8) = L;
}

// ---------------------------------------------------------------------------
// gemm_pack: C = A(4096x1024) * B(1024x1024) + bias, 3-term split MFMA.
// 64x64 tile / block, 4 waves as 2x2 of 32x32, mfma_f32_16x16x32_bf16.
// mode 0: epilogue packs (scale*(C+bias)) into QK attention layout
//         [b][h][s16][d8][16][8]   (used for Q with scale=1/8, and K)
// mode 1: packs into V attention layout [b][h][d16][s8][16][8]
// mode 2: fp32 store with final transpose: out[b][n][s] = C[m][n]+bias[n]
// ---------------------------------------------------------------------------
__global__ __launch_bounds__(256) void gemm_pack(
    const ushort_t* __restrict__ Ahi, const ushort_t* __restrict__ Alo,
    const ushort_t* __restrict__ Bhi, const ushort_t* __restrict__ Blo,
    const float* __restrict__ bias, ushort_t* __restrict__ Ohi,
    ushort_t* __restrict__ Olo, float* __restrict__ Ofp, float scale,
    int mode) {
  __shared__ ushort_t lhi[4096], llo[4096];
  const int m0 = blockIdx.y * 64;
  const int n0 = blockIdx.x * 64;
  const int lane = threadIdx.x & 63;
  const int wv = threadIdx.x >> 6;
  const int wr = wv >> 1, wc = wv & 1;
  const int l15 = lane & 15, l4 = lane >> 4;

  f32x4 acc[2][2] = {};

  size_t Ab[2], Bb[2];
#pragma unroll
  for (int mi = 0; mi < 2; ++mi)
    Ab[mi] = (size_t)((m0 >> 4) + wr * 2 + mi) * (KB * 128) + l4 * 128 + l15 * 8;
#pragma unroll
  for (int ni = 0; ni < 2; ++ni)
    Bb[ni] = (size_t)((n0 >> 4) + wc * 2 + ni) * (KB * 128) + l4 * 128 + l15 * 8;

#pragma unroll 2
  for (int ks = 0; ks < HID / 32; ++ks) {
    short8 ah[2], al[2], bh[2], bl[2];
#pragma unroll
    for (int mi = 0; mi < 2; ++mi) {
      ah[mi] = *(const short8*)(Ahi + Ab[mi] + ks * 512);
      al[mi] = *(const short8*)(Alo + Ab[mi] + ks * 512);
    }
#pragma unroll
    for (int ni = 0; ni < 2; ++ni) {
      bh[ni] = *(const short8*)(Bhi + Bb[ni] + ks * 512);
      bl[ni] = *(const short8*)(Blo + Bb[ni] + ks * 512);
    }
#pragma unroll
    for (int mi = 0; mi < 2; ++mi)
#pragma unroll
      for (int ni = 0; ni < 2; ++ni) {
        acc[mi][ni] = __builtin_amdgcn_mfma_f32_16x16x32_bf16(al[mi], bh[ni], acc[mi][ni], 0, 0, 0);
        acc[mi][ni] = __builtin_amdgcn_mfma_f32_16x16x32_bf16(ah[mi], bl[ni], acc[mi][ni], 0, 0, 0);
        acc[mi][ni] = __builtin_amdgcn_mfma_f32_16x16x32_bf16(ah[mi], bh[ni], acc[mi][ni], 0, 0, 0);
      }
  }

  if (mode < 2) {
    // C/D frag: col = l15, row = l4*4 + i  (m89-verified layout)
#pragma unroll
    for (int mi = 0; mi < 2; ++mi)
#pragma unroll
      for (int ni = 0; ni < 2; ++ni) {
        int col = wc * 32 + ni * 16 + l15;  // local n (= d within head)
        float bvv = bias[n0 + col];
#pragma unroll
        for (int i = 0; i < 4; ++i) {
          int row = wr * 32 + mi * 16 + l4 * 4 + i;  // local m (= s local)
          float v = (acc[mi][ni][i] + bvv) * scale;
          ushort_t hh, ll;
          bsplit(v, hh, ll);
          int loc = (mode == 0)
                        ? (((row >> 4) * 8 + (col >> 3)) * 128 + (row & 15) * 8 + (col & 7))
                        : (((col >> 4) * 8 + (row >> 3)) * 128 + (col & 15) * 8 + (row & 7));
          lhi[loc] = hh;
          llo[loc] = ll;
        }
      }
    __syncthreads();
    const int hd = n0 >> 6;              // head (BN=64 == one head)
    const int b_ = m0 >> 11;             // batch
    const int s0 = m0 & (S_LEN - 1);     // seq base
    const size_t hb = (size_t)(b_ * NH + hd) * PERHEAD;
    int t = threadIdx.x;
    size_t dst;
    if (mode == 0) {
      int m16loc = (t * 16) >> 10, rem = (t * 16) & 1023;
      dst = hb + (size_t)((s0 >> 4) + m16loc) * 1024 + rem;
    } else {
      int dg = (t * 16) >> 10, rem = (t * 16) & 1023;
      dst = hb + (size_t)dg * 32768 + (size_t)(s0 >> 3) * 128 + rem;
    }
    *(short8*)(Ohi + dst) = *(const short8*)&lhi[t * 16];
    *(short8*)(Ohi + dst + 8) = *(const short8*)&lhi[t * 16 + 8];
    *(short8*)(Olo + dst) = *(const short8*)&llo[t * 16];
    *(short8*)(Olo + dst + 8) = *(const short8*)&llo[t * 16 + 8];
  } else {
    // final: out[b][n][s] ; rows of a frag are 4 consecutive s -> float4 store
#pragma unroll
    for (int mi = 0; mi < 2; ++mi)
#pragma unroll
      for (int ni = 0; ni < 2; ++ni) {
        int col = n0 + wc * 32 + ni * 16 + l15;
        float bvv = bias[col];
        int m = m0 + wr * 32 + mi * 16 + l4 * 4;
        int b_ = m >> 11, s = m & (S_LEN - 1);
        f32x4 v = acc[mi][ni];
        v[0] += bvv; v[1] += bvv; v[2] += bvv; v[3] += bvv;
        *(f32x4*)(Ofp + (size_t)(b_ * HID + col) * S_LEN + s) = v;
      }
  }
}

// ---------------------------------------------------------------------------
// Flash attention. Block = (q-tile 64, head, batch); 4 waves, wave owns 16 q
// rows. KBLK=64. Q pre-scaled by 1/8 in its projection. Online softmax with
// 16-lane shfl_xor row reductions. P relayout via per-wave PRIVATE LDS (no
// cross-wave sharing -> no __syncthreads needed in the K-loop; intra-wave
// lgkmcnt ordering is compiler-inserted). Output x written in A-fragment
// layout for the O-projection GEMM.
// ---------------------------------------------------------------------------
__global__ __launch_bounds__(256) void attn_kernel(
    const ushort_t* __restrict__ Qhi, const ushort_t* __restrict__ Qlo,
    const ushort_t* __restrict__ Khi, const ushort_t* __restrict__ Klo,
    const ushort_t* __restrict__ Vhi, const ushort_t* __restrict__ Vlo,
    const int* __restrict__ mask, ushort_t* __restrict__ Xhi,
    ushort_t* __restrict__ Xlo) {
  __shared__ ushort_t Phi[4][1024], Plo[4][1024];
  __shared__ ushort_t xh[4096], xl[4096];
  const int qb = blockIdx.x, h = blockIdx.y, b = blockIdx.z;
  const int lane = threadIdx.x & 63, wv = threadIdx.x >> 6;
  const int l15 = lane & 15, l4 = lane >> 4;
  const size_t hb = (size_t)(b * NH + h) * PERHEAD;
  const int q16 = qb * 4 + wv;

  // Q frags resident (kk = K-step over D=64)
  short8 qh[2], ql[2];
#pragma unroll
  for (int kk = 0; kk < 2; ++kk) {
    size_t o = hb + ((size_t)(q16 * 8 + kk * 4 + l4) * 16 + l15) * 8;
    qh[kk] = *(const short8*)(Qhi + o);
    ql[kk] = *(const short8*)(Qlo + o);
  }

  // invariant per-lane fragment offsets
  const size_t kfrag = hb + ((size_t)(l4)*16 + l15) * 8;  // + s16*1024 + kk*512
  const int* mrow = mask + b * S_LEN;

  f32x4 o_acc[4] = {};
  float m_r[4], l_r[4];
#pragma unroll
  for (int i = 0; i < 4; ++i) { m_r[i] = -1e30f; l_r[i] = 0.f; }

  for (int kt = 0; kt < S_LEN / 64; ++kt) {
    // ---- scores: S = Q K^T (3-term split), mask replace with -1e9 ----
    f32x4 sc[4];
#pragma unroll
    for (int cg = 0; cg < 4; ++cg) {
      f32x4 a = {};
      size_t ko = kfrag + (size_t)(kt * 4 + cg) * 1024;
#pragma unroll
      for (int kk = 0; kk < 2; ++kk) {
        short8 kh = *(const short8*)(Khi + ko + kk * 512);
        short8 kl = *(const short8*)(Klo + ko + kk * 512);
        a = __builtin_amdgcn_mfma_f32_16x16x32_bf16(ql[kk], kh, a, 0, 0, 0);
        a = __builtin_amdgcn_mfma_f32_16x16x32_bf16(qh[kk], kl, a, 0, 0, 0);
        a = __builtin_amdgcn_mfma_f32_16x16x32_bf16(qh[kk], kh, a, 0, 0, 0);
      }
      int mk = mrow[kt * 64 + cg * 16 + l15];
      if (mk == 0) { a[0] = -1e9f; a[1] = -1e9f; a[2] = -1e9f; a[3] = -1e9f; }
      sc[cg] = a;
    }
    // ---- row max (per row: 4 in-lane cg + 16-lane butterfly) ----
    float tmax[4];
#pragma unroll
    for (int i = 0; i < 4; ++i)
      tmax[i] = fmaxf(fmaxf(sc[0][i], sc[1][i]), fmaxf(sc[2][i], sc[3][i]));
#pragma unroll
    for (int i = 0; i < 4; ++i) {
#pragma unroll
      for (int off = 1; off < 16; off <<= 1)
        tmax[i] = fmaxf(tmax[i], __shfl_xor(tmax[i], off));
    }
    float fs[4];
#pragma unroll
    for (int i = 0; i < 4; ++i) {
      float mn = fmaxf(m_r[i], tmax[i]);
      fs[i] = __expf(m_r[i] - mn);
      m_r[i] = mn;
      l_r[i] *= fs[i];
#pragma unroll
      for (int dg = 0; dg < 4; ++dg) o_acc[dg][i] *= fs[i];
    }
    // ---- P = exp(S - m), split to LDS in A-frag layout, row sums ----
    float tsum[4] = {0.f, 0.f, 0.f, 0.f};
#pragma unroll
    for (int cg = 0; cg < 4; ++cg) {
#pragma unroll
      for (int i = 0; i < 4; ++i) {
        float p = __expf(sc[cg][i] - m_r[i]);
        tsum[i] += p;
        ushort_t ph, pl;
        bsplit(p, ph, pl);
        int loc = ((cg * 2 + (l15 >> 3)) * 16 + l4 * 4 + i) * 8 + (l15 & 7);
        Phi[wv][loc] = ph;
        Plo[wv][loc] = pl;
      }
    }
#pragma unroll
    for (int i = 0; i < 4; ++i) {
#pragma unroll
      for (int off = 1; off < 16; off <<= 1) tsum[i] += __shfl_xor(tsum[i], off);
      l_r[i] += tsum[i];
    }
    // ---- O += P V (3-term split); Phi/Plo are wave-private ----
    const size_t vbase = kfrag + (size_t)kt * 1024;  // + dg*32768 + kk*512
#pragma unroll
    for (int kk = 0; kk < 2; ++kk) {
      const short8 ph = *(const short8*)&Phi[wv][(kk * 64 + lane) * 8];
      const short8 pl = *(const short8*)&Plo[wv][(kk * 64 + lane) * 8];
#pragma unroll
      for (int dg = 0; dg < 4; ++dg) {
        size_t vo = vbase + (size_t)dg * 32768 + kk * 512;
        short8 vh = *(const short8*)(Vhi + vo);
        short8 vl = *(const short8*)(Vlo + vo);
        o_acc[dg] = __builtin_amdgcn_mfma_f32_16x16x32_bf16(pl, vh, o_acc[dg], 0, 0, 0);
        o_acc[dg] = __builtin_amdgcn_mfma_f32_16x16x32_bf16(ph, vl, o_acc[dg], 0, 0, 0);
        o_acc[dg] = __builtin_amdgcn_mfma_f32_16x16x32_bf16(ph, vh, o_acc[dg], 0, 0, 0);
      }
    }
  }
  // ---- epilogue: x = O / l, pack to A-layout for O-projection ----
#pragma unroll
  for (int dg = 0; dg < 4; ++dg) {
#pragma unroll
    for (int i = 0; i < 4; ++i) {
      float val = o_acc[dg][i] / l_r[i];
      int mloc = wv * 16 + l4 * 4 + i;
      int d = dg * 16 + l15;
      int loc = ((mloc >> 4) * 8 + (d >> 3)) * 128 + (mloc & 15) * 8 + (d & 7);
      ushort_t hh, ll;
      bsplit(val, hh, ll);
      xh[loc] = hh;
      xl[loc] = ll;
    }
  }
  __syncthreads();  // xh/xl ARE cross-wave: cooperative write-out below
  const int m0 = b * S_LEN + qb * 64;
  int t = threadIdx.x;
  int m16loc = (t * 16) >> 10, rem = (t * 16) & 1023;
  size_t dst = (size_t)((m0 >> 4) + m16loc) * 16384 + (size_t)h * 1024 + rem;
  *(short8*)(Xhi + dst) = *(const short8*)&xh[t * 16];
  *(short8*)(Xhi + dst + 8) = *(const short8*)&xh[t * 16 + 8];
  *(short8*)(Xlo + dst) = *(const short8*)&xl[t * 16];
  *(short8*)(Xlo + dst + 8) = *(const short8*)&xl[t * 16 + 8];
}

// ---------------------------------------------------------------------------
extern "C" void kernel_launch(void* const* d_in, const int* in_sizes, int n_in,
                              void* d_out, int out_size, void* d_ws,
                              size_t ws_size, hipStream_t stream) {
  (void)in_sizes; (void)n_in; (void)out_size; (void)ws_size;
  const float* query = (const float*)d_in[0];
  const float* key = (const float*)d_in[1];
  const float* value = (const float*)d_in[2];
  const int* mask = (const int*)d_in[3];
  const float* Wq = (const float*)d_in[4];
  const float* bq = (const float*)d_in[5];
  const float* Wk = (const float*)d_in[6];
  const float* bk = (const float*)d_in[7];
  const float* Wv = (const float*)d_in[8];
  const float* bv = (const float*)d_in[9];
  const float* Wo = (const float*)d_in[10];
  const float* bo = (const float*)d_in[11];
  float* out = (float*)d_out;

  // workspace layout (ushort elems). Total = 40 Mi elems = 80 MiB.
  const size_t EL = (size_t)MTOT * HID;  // 4 Mi elems
  const size_t WEL = (size_t)HID * HID;  // 1 Mi elems
  ushort_t* p = (ushort_t*)d_ws;
  ushort_t* X0h = p;            ushort_t* X0l = X0h + EL;
  ushort_t* X1h = X0l + EL;     ushort_t* X1l = X1h + EL;
  ushort_t* X2h = X1l + EL;     ushort_t* X2l = X2h + EL;
  ushort_t* W0h = X2l + EL;     ushort_t* W0l = W0h + WEL;
  ushort_t* W1h = W0l + WEL;    ushort_t* W1l = W1h + WEL;
  ushort_t* W2h = W1l + WEL;    ushort_t* W2l = W2h + WEL;
  ushort_t* W3h = W2l + WEL;    ushort_t* W3l = W3h + WEL;
  ushort_t* Qh = W3l + WEL;     ushort_t* Ql = Qh + EL;

  // 1) pack activations (A-side) and weights (B-side)
  pack_mat<<<dim3(2048), dim3(256), 0, stream>>>(query, X0h, X0l, 0);
  pack_mat<<<dim3(2048), dim3(256), 0, stream>>>(key, X1h, X1l, 0);
  pack_mat<<<dim3(2048), dim3(256), 0, stream>>>(value, X2h, X2l, 0);
  pack_mat<<<dim3(512), dim3(256), 0, stream>>>(Wq, W0h, W0l, 1);
  pack_mat<<<dim3(512), dim3(256), 0, stream>>>(Wk, W1h, W1l, 1);
  pack_mat<<<dim3(512), dim3(256), 0, stream>>>(Wv, W2h, W2l, 1);
  pack_mat<<<dim3(512), dim3(256), 0, stream>>>(Wo, W3h, W3l, 1);

  // 2) projections (buffer reuse: K out -> X0, V out -> X1)
  dim3 gg(HID / 64, MTOT / 64);
  gemm_pack<<<gg, 256, 0, stream>>>(X0h, X0l, W0h, W0l, bq, Qh, Ql, nullptr,
                                    0.125f, 0);  // Q (pre-scaled 1/sqrt(Dh))
  gemm_pack<<<gg, 256, 0, stream>>>(X1h, X1l, W1h, W1l, bk, X0h, X0l, nullptr,
                                    1.0f, 0);    // K
  gemm_pack<<<gg, 256, 0, stream>>>(X2h, X2l, W2h, W2l, bv, X1h, X1l, nullptr,
                                    1.0f, 1);    // V

  // 3) attention: Q=(Qh,Ql) K=(X0) V=(X1) -> x packed into X2
  attn_kernel<<<dim3(S_LEN / 64, NH, 2), 256, 0, stream>>>(
      Qh, Ql, X0h, X0l, X1h, X1l, mask, X2h, X2l);

  // 4) output projection + bias + transpose -> d_out
  gemm_pack<<<gg, 256, 0, stream>>>(X2h, X2l, W3h, W3l, bo, nullptr, nullptr,
                                    out, 1.0f, 2);
}

// Round 5
// 428.016 us; speedup vs baseline: 1.2055x; 1.2055x over previous
//
#include <hip/hip_runtime.h>

// ---------------------------------------------------------------------------
// MHA: out = ((softmax(mask((XqWq+bq)(XkWk+bk)^T/8)) (XvWv+bv)) Wo + bo)^T
// B=2, S=2048, HID=1024, H=16, Dh=64.  All fp32 in/out.
// 3-term bf16 hi/lo split MFMA everywhere. Attention uses swapped operands
// (mfma(K,Q), mfma(V,P)) so softmax rows are lane-local, with LDS-staged K/V.
// ---------------------------------------------------------------------------

typedef unsigned short ushort_t;
typedef unsigned long long ull_t;
typedef __attribute__((ext_vector_type(8))) short short8;
typedef __attribute__((ext_vector_type(4))) float f32x4;

#define S_LEN 2048
#define HID 1024
#define NH 16
#define MTOT 4096            // B*S rows
#define KB 128               // HID/8 k8-blocks
#define PERHEAD 131072       // per-(b,h) packed elems (S*64)
#define QSCALE 0.18033688011112042f   // (1/8) * log2(e): softmax in exp2 domain

// RNE fp32 -> bf16 split (hi RNE, lo RNE of residual)
__device__ __forceinline__ void bsplit(float x, ushort_t& h, ushort_t& l) {
  unsigned u = __float_as_uint(x);
  unsigned hr = (u + 0x7fffu + ((u >> 16) & 1u)) >> 16;
  h = (ushort_t)hr;
  float hf = __uint_as_float(hr << 16);
  float r = x - hf;
  unsigned u2 = __float_as_uint(r);
  l = (ushort_t)((u2 + 0x7fffu + ((u2 >> 16) & 1u)) >> 16);
}

// trunc-hi + cvt_pk RNE-lo split of 4 floats -> two u64 (hi-pair, lo-pair)
__device__ __forceinline__ void qsplit4(float v0, float v1, float v2, float v3,
                                        ull_t& hi, ull_t& lo) {
  unsigned u0 = __float_as_uint(v0), u1 = __float_as_uint(v1);
  unsigned u2 = __float_as_uint(v2), u3 = __float_as_uint(v3);
  unsigned h01 = (u0 >> 16) | (u1 & 0xffff0000u);
  unsigned h23 = (u2 >> 16) | (u3 & 0xffff0000u);
  float r0 = v0 - __uint_as_float(u0 & 0xffff0000u);
  float r1 = v1 - __uint_as_float(u1 & 0xffff0000u);
  float r2 = v2 - __uint_as_float(u2 & 0xffff0000u);
  float r3 = v3 - __uint_as_float(u3 & 0xffff0000u);
  unsigned l01, l23;
  asm("v_cvt_pk_bf16_f32 %0, %1, %2" : "=v"(l01) : "v"(r0), "v"(r1));
  asm("v_cvt_pk_bf16_f32 %0, %1, %2" : "=v"(l23) : "v"(r2), "v"(r3));
  hi = (ull_t)h01 | ((ull_t)h23 << 32);
  lo = (ull_t)l01 | ((ull_t)l23 << 32);
}

__device__ __forceinline__ void gload16(const ushort_t* g, ushort_t* l) {
  __builtin_amdgcn_global_load_lds(
      (const __attribute__((address_space(1))) unsigned int*)g,
      (__attribute__((address_space(3))) unsigned int*)l, 16, 0, 0);
}

// ---------------------------------------------------------------------------
__global__ __launch_bounds__(256) void pack_mat(const float* __restrict__ src,
                                                ushort_t* __restrict__ hi,
                                                ushort_t* __restrict__ lo,
                                                int bmode) {
  int tid = blockIdx.x * 256 + threadIdx.x;
  int r = tid & 15;
  int k8 = (tid >> 4) & (KB - 1);
  int o16 = tid >> 11;
  float v[8];
  if (bmode == 0) {
    const float* s = src + (size_t)(o16 * 16 + r) * HID + k8 * 8;
    const f32x4 f0 = *(const f32x4*)s;
    const f32x4 f1 = *(const f32x4*)(s + 4);
#pragma unroll
    for (int j = 0; j < 4; ++j) { v[j] = f0[j]; v[4 + j] = f1[j]; }
  } else {
#pragma unroll
    for (int j = 0; j < 8; ++j)
      v[j] = src[(size_t)(k8 * 8 + j) * HID + o16 * 16 + r];
  }
  short8 H, L;
#pragma unroll
  for (int j = 0; j < 8; ++j) {
    ushort_t h, l;
    bsplit(v[j], h, l);
    H[j] = (short)h;
    L[j] = (short)l;
  }
  *(short8*)(hi + (size_t)tid * 8) = H;
  *(short8*)(lo + (size_t)tid * 8) = L;
}

__global__ __launch_bounds__(256) void mask_to_float(const int* __restrict__ m,
                                                     float* __restrict__ mf) {
  int i = blockIdx.x * 256 + threadIdx.x;
  mf[i] = m[i] ? 0.f : -1e9f;
}

// ---------------------------------------------------------------------------
// gemm_pack: C = A(4096x1024) * B(1024x1024) + bias, 3-term split MFMA.
// 128x64 tile, 4 waves 2x2 (wave = 64 rows x 32 cols, 4x2 frags).
// mode 0: pack (scale*(C+bias)) -> QK layout [b][h][s16][d8][16][8]
// mode 1: pack -> V layout [b][h][d16][s8][16][8]
// mode 2: fp32 store transposed: out[b][n][s]
// ---------------------------------------------------------------------------
__global__ __launch_bounds__(256) void gemm_pack(
    const ushort_t* __restrict__ Ahi, const ushort_t* __restrict__ Alo,
    const ushort_t* __restrict__ Bhi, const ushort_t* __restrict__ Blo,
    const float* __restrict__ bias, ushort_t* __restrict__ Ohi,
    ushort_t* __restrict__ Olo, float* __restrict__ Ofp, float scale,
    int mode) {
  __shared__ ushort_t lhi[8192], llo[8192];
  const int m0 = blockIdx.y * 128;
  const int n0 = blockIdx.x * 64;
  const int lane = threadIdx.x & 63;
  const int wv = threadIdx.x >> 6;
  const int wr = wv >> 1, wc = wv & 1;
  const int l15 = lane & 15, l4 = lane >> 4;

  f32x4 acc[4][2] = {};

  size_t Ab[4], Bb[2];
#pragma unroll
  for (int mi = 0; mi < 4; ++mi)
    Ab[mi] = (size_t)((m0 >> 4) + wr * 4 + mi) * 16384 + l4 * 128 + l15 * 8;
#pragma unroll
  for (int ni = 0; ni < 2; ++ni)
    Bb[ni] = (size_t)((n0 >> 4) + wc * 2 + ni) * 16384 + l4 * 128 + l15 * 8;

#pragma unroll 2
  for (int ks = 0; ks < HID / 32; ++ks) {
    short8 ah[4], al[4], bh[2], bl[2];
#pragma unroll
    for (int mi = 0; mi < 4; ++mi) {
      ah[mi] = *(const short8*)(Ahi + Ab[mi] + ks * 512);
      al[mi] = *(const short8*)(Alo + Ab[mi] + ks * 512);
    }
#pragma unroll
    for (int ni = 0; ni < 2; ++ni) {
      bh[ni] = *(const short8*)(Bhi + Bb[ni] + ks * 512);
      bl[ni] = *(const short8*)(Blo + Bb[ni] + ks * 512);
    }
#pragma unroll
    for (int mi = 0; mi < 4; ++mi)
#pragma unroll
      for (int ni = 0; ni < 2; ++ni) {
        acc[mi][ni] = __builtin_amdgcn_mfma_f32_16x16x32_bf16(al[mi], bh[ni], acc[mi][ni], 0, 0, 0);
        acc[mi][ni] = __builtin_amdgcn_mfma_f32_16x16x32_bf16(ah[mi], bl[ni], acc[mi][ni], 0, 0, 0);
        acc[mi][ni] = __builtin_amdgcn_mfma_f32_16x16x32_bf16(ah[mi], bh[ni], acc[mi][ni], 0, 0, 0);
      }
  }

  if (mode < 2) {
#pragma unroll
    for (int mi = 0; mi < 4; ++mi)
#pragma unroll
      for (int ni = 0; ni < 2; ++ni) {
        int col = wc * 32 + ni * 16 + l15;  // 0..63 (= d within head)
        float bvv = bias[n0 + col];
#pragma unroll
        for (int i = 0; i < 4; ++i) {
          int row = wr * 64 + mi * 16 + l4 * 4 + i;  // 0..127 (s local)
          float v = (acc[mi][ni][i] + bvv) * scale;
          ushort_t hh, ll;
          bsplit(v, hh, ll);
          int loc = (mode == 0)
                        ? (((row >> 4) * 8 + (col >> 3)) * 128 + (row & 15) * 8 + (col & 7))
                        : (((col >> 4) * 16 + (row >> 3)) * 128 + (col & 15) * 8 + (row & 7));
          lhi[loc] = hh;
          llo[loc] = ll;
        }
      }
    __syncthreads();
    const int hd = n0 >> 6;              // head (BN=64 == one head)
    const int b_ = m0 >> 11;             // batch
    const int s0 = m0 & (S_LEN - 1);     // seq base
    const size_t hb = (size_t)(b_ * NH + hd) * PERHEAD;
#pragma unroll
    for (int r2 = 0; r2 < 2; ++r2) {
      int t = r2 * 256 + threadIdx.x;
      size_t dst;
      if (mode == 0) {
        int m16loc = (t * 16) >> 10, rem = (t * 16) & 1023;
        dst = hb + (size_t)((s0 >> 4) + m16loc) * 1024 + rem;
      } else {
        int dg = (t * 16) >> 11, rem = (t * 16) & 2047;
        dst = hb + (size_t)dg * 32768 + (size_t)(s0 >> 3) * 128 + rem;
      }
      *(short8*)(Ohi + dst) = *(const short8*)&lhi[t * 16];
      *(short8*)(Ohi + dst + 8) = *(const short8*)&lhi[t * 16 + 8];
      *(short8*)(Olo + dst) = *(const short8*)&llo[t * 16];
      *(short8*)(Olo + dst + 8) = *(const short8*)&llo[t * 16 + 8];
    }
  } else {
#pragma unroll
    for (int mi = 0; mi < 4; ++mi)
#pragma unroll
      for (int ni = 0; ni < 2; ++ni) {
        int col = n0 + wc * 32 + ni * 16 + l15;
        float bvv = bias[col];
        int m = m0 + wr * 64 + mi * 16 + l4 * 4;
        int b_ = m >> 11, s = m & (S_LEN - 1);
        f32x4 v = acc[mi][ni];
        v[0] += bvv; v[1] += bvv; v[2] += bvv; v[3] += bvv;
        *(f32x4*)(Ofp + (size_t)(b_ * HID + col) * S_LEN + s) = v;
      }
  }
}

// ---------------------------------------------------------------------------
// Flash attention, swapped operands. Block = (qb, h, b): 128 q-rows, 4 waves
// x 32 q-rows (2 q16-frags each). K/V tiles (64 keys) staged in LDS via
// global_load_lds, shared by all waves. Scores S^T = mfma(K,Q): lane holds
// q = l15, keys = cg*16 + l4*4 + i  -> in-lane softmax + 2 shuffles.
// P -> LDS as b64 (conflict-free), PV: O^T = mfma(V^T, P).
// ---------------------------------------------------------------------------
__global__ __launch_bounds__(256) void attn_kernel(
    const ushort_t* __restrict__ Qhi, const ushort_t* __restrict__ Qlo,
    const ushort_t* __restrict__ Khi, const ushort_t* __restrict__ Klo,
    const ushort_t* __restrict__ Vhi, const ushort_t* __restrict__ Vlo,
    const float* __restrict__ maskF, ushort_t* __restrict__ Xhi,
    ushort_t* __restrict__ Xlo) {
  __shared__ ushort_t KtH[4096], KtL[4096], VtH[4096], VtL[4096];
  __shared__ ushort_t PH[4][2][1024], PL[4][2][1024];
  const int qb = blockIdx.x, h = blockIdx.y, b = blockIdx.z;
  const int lane = threadIdx.x & 63, wv = threadIdx.x >> 6;
  const int l15 = lane & 15, l4 = lane >> 4;
  const size_t hb = (size_t)(b * NH + h) * PERHEAD;

  // Q fragments resident (as B-operand: col=l15=q, k=d)
  short8 qh[2][2], ql[2][2];
#pragma unroll
  for (int qi = 0; qi < 2; ++qi)
#pragma unroll
    for (int kk = 0; kk < 2; ++kk) {
      size_t o = hb + (size_t)(qb * 8 + wv * 2 + qi) * 1024 + (kk * 4 + l4) * 128 + l15 * 8;
      qh[qi][kk] = *(const short8*)(Qhi + o);
      ql[qi][kk] = *(const short8*)(Qlo + o);
    }

  const float* mrow = maskF + b * S_LEN;
  f32x4 o_acc[2][4] = {};
  float m_r[2] = {-1e30f, -1e30f}, l_r[2] = {0.f, 0.f};

  for (int kt = 0; kt < S_LEN / 64; ++kt) {
    __syncthreads();  // previous tile's compute done before overwrite
    // ---- stage K/V tile (64 keys) into LDS, linear copies ----
#pragma unroll
    for (int c = 0; c < 2; ++c) {
      int chunk = wv * 2 + c;                       // 0..7
      size_t ko = hb + (size_t)kt * 4096 + chunk * 512 + lane * 8;
      gload16(Khi + ko, &KtH[chunk * 512]);
      gload16(Klo + ko, &KtL[chunk * 512]);
      int dg = chunk >> 1, hf = chunk & 1;
      size_t vo = hb + (size_t)dg * 32768 + (size_t)kt * 1024 + hf * 512 + lane * 8;
      gload16(Vhi + vo, &VtH[chunk * 512]);
      gload16(Vlo + vo, &VtL[chunk * 512]);
    }
    f32x4 mf[4];
#pragma unroll
    for (int cg = 0; cg < 4; ++cg)
      mf[cg] = *(const f32x4*)(mrow + kt * 64 + cg * 16 + l4 * 4);
    asm volatile("s_waitcnt vmcnt(0)" ::: "memory");
    __syncthreads();

    // ---- scores S^T = K Q^T (3-term), + mask ----
    f32x4 sc[2][4];
#pragma unroll
    for (int cg = 0; cg < 4; ++cg) {
      short8 kh[2], kl[2];
#pragma unroll
      for (int kk = 0; kk < 2; ++kk) {
        int e = cg * 1024 + (kk * 4 + l4) * 128 + l15 * 8;
        kh[kk] = *(const short8*)&KtH[e];
        kl[kk] = *(const short8*)&KtL[e];
      }
#pragma unroll
      for (int qi = 0; qi < 2; ++qi) {
        f32x4 a = {};
#pragma unroll
        for (int kk = 0; kk < 2; ++kk) {
          a = __builtin_amdgcn_mfma_f32_16x16x32_bf16(kl[kk], qh[qi][kk], a, 0, 0, 0);
          a = __builtin_amdgcn_mfma_f32_16x16x32_bf16(kh[kk], ql[qi][kk], a, 0, 0, 0);
          a = __builtin_amdgcn_mfma_f32_16x16x32_bf16(kh[kk], qh[qi][kk], a, 0, 0, 0);
        }
        a[0] += mf[cg][0]; a[1] += mf[cg][1]; a[2] += mf[cg][2]; a[3] += mf[cg][3];
        sc[qi][cg] = a;
      }
    }

    // ---- online softmax (exp2 domain), P -> LDS ----
#pragma unroll
    for (int qi = 0; qi < 2; ++qi) {
      float tm = fmaxf(fmaxf(fmaxf(sc[qi][0][0], sc[qi][0][1]), fmaxf(sc[qi][0][2], sc[qi][0][3])),
                       fmaxf(fmaxf(sc[qi][1][0], sc[qi][1][1]), fmaxf(sc[qi][1][2], sc[qi][1][3])));
      float tm2 = fmaxf(fmaxf(fmaxf(sc[qi][2][0], sc[qi][2][1]), fmaxf(sc[qi][2][2], sc[qi][2][3])),
                        fmaxf(fmaxf(sc[qi][3][0], sc[qi][3][1]), fmaxf(sc[qi][3][2], sc[qi][3][3])));
      tm = fmaxf(tm, tm2);
      tm = fmaxf(tm, __shfl_xor(tm, 16));
      tm = fmaxf(tm, __shfl_xor(tm, 32));
      float mn = fmaxf(m_r[qi], tm);
      float fs = exp2f(m_r[qi] - mn);
      m_r[qi] = mn;
#pragma unroll
      for (int dg = 0; dg < 4; ++dg) o_acc[qi][dg] *= fs;
      float ts = 0.f;
#pragma unroll
      for (int cg = 0; cg < 4; ++cg) {
        float p0 = exp2f(sc[qi][cg][0] - mn);
        float p1 = exp2f(sc[qi][cg][1] - mn);
        float p2 = exp2f(sc[qi][cg][2] - mn);
        float p3 = exp2f(sc[qi][cg][3] - mn);
        ts += (p0 + p1) + (p2 + p3);
        ull_t hi, lo;
        qsplit4(p0, p1, p2, p3, hi, lo);
        int e = (cg * 2 + (l4 >> 1)) * 128 + l15 * 8 + (l4 & 1) * 4;
        *(ull_t*)&PH[wv][qi][e] = hi;
        *(ull_t*)&PL[wv][qi][e] = lo;
      }
      ts += __shfl_xor(ts, 16);
      ts += __shfl_xor(ts, 32);
      l_r[qi] = l_r[qi] * fs + ts;
    }

    // ---- O^T += V^T P (3-term) ----
#pragma unroll
    for (int kk = 0; kk < 2; ++kk) {
      short8 vh[4], vl[4];
#pragma unroll
      for (int dg = 0; dg < 4; ++dg) {
        int e = dg * 1024 + (kk * 4 + l4) * 128 + l15 * 8;
        vh[dg] = *(const short8*)&VtH[e];
        vl[dg] = *(const short8*)&VtL[e];
      }
#pragma unroll
      for (int qi = 0; qi < 2; ++qi) {
        int pe = (kk * 4 + l4) * 128 + l15 * 8;
        short8 pbh = *(const short8*)&PH[wv][qi][pe];
        short8 pbl = *(const short8*)&PL[wv][qi][pe];
#pragma unroll
        for (int dg = 0; dg < 4; ++dg) {
          o_acc[qi][dg] = __builtin_amdgcn_mfma_f32_16x16x32_bf16(vh[dg], pbl, o_acc[qi][dg], 0, 0, 0);
          o_acc[qi][dg] = __builtin_amdgcn_mfma_f32_16x16x32_bf16(vl[dg], pbh, o_acc[qi][dg], 0, 0, 0);
          o_acc[qi][dg] = __builtin_amdgcn_mfma_f32_16x16x32_bf16(vh[dg], pbh, o_acc[qi][dg], 0, 0, 0);
        }
      }
    }
  }

  // ---- epilogue: x = O/l, direct global store in A-frag layout ----
#pragma unroll
  for (int qi = 0; qi < 2; ++qi) {
    float rl = 1.0f / l_r[qi];
    int m16 = b * 128 + qb * 8 + wv * 2 + qi;
#pragma unroll
    for (int dg = 0; dg < 4; ++dg) {
      float v0 = o_acc[qi][dg][0] * rl;
      float v1 = o_acc[qi][dg][1] * rl;
      float v2 = o_acc[qi][dg][2] * rl;
      float v3 = o_acc[qi][dg][3] * rl;
      ull_t hi, lo;
      qsplit4(v0, v1, v2, v3, hi, lo);
      size_t dst = (size_t)m16 * 16384 + (size_t)(h * 8 + dg * 2 + (l4 >> 1)) * 128 + l15 * 8 + (l4 & 1) * 4;
      *(ull_t*)(Xhi + dst) = hi;
      *(ull_t*)(Xlo + dst) = lo;
    }
  }
}

// ---------------------------------------------------------------------------
extern "C" void kernel_launch(void* const* d_in, const int* in_sizes, int n_in,
                              void* d_out, int out_size, void* d_ws,
                              size_t ws_size, hipStream_t stream) {
  (void)in_sizes; (void)n_in; (void)out_size; (void)ws_size;
  const float* query = (const float*)d_in[0];
  const float* key = (const float*)d_in[1];
  const float* value = (const float*)d_in[2];
  const int* mask = (const int*)d_in[3];
  const float* Wq = (const float*)d_in[4];
  const float* bq = (const float*)d_in[5];
  const float* Wk = (const float*)d_in[6];
  const float* bk = (const float*)d_in[7];
  const float* Wv = (const float*)d_in[8];
  const float* bv = (const float*)d_in[9];
  const float* Wo = (const float*)d_in[10];
  const float* bo = (const float*)d_in[11];
  float* out = (float*)d_out;

  // workspace layout (ushort elems). Total = 40 Mi elems = 80 MiB
  // (identical footprint to the round-2 PASSED layout; maskF aliases W0h,
  // which is dead after the Q-projection GEMM).
  const size_t EL = (size_t)MTOT * HID;  // 4 Mi elems
  const size_t WEL = (size_t)HID * HID;  // 1 Mi elems
  ushort_t* p = (ushort_t*)d_ws;
  ushort_t* X0h = p;            ushort_t* X0l = X0h + EL;
  ushort_t* X1h = X0l + EL;     ushort_t* X1l = X1h + EL;
  ushort_t* X2h = X1l + EL;     ushort_t* X2l = X2h + EL;
  ushort_t* W0h = X2l + EL;     ushort_t* W0l = W0h + WEL;
  ushort_t* W1h = W0l + WEL;    ushort_t* W1l = W1h + WEL;
  ushort_t* W2h = W1l + WEL;    ushort_t* W2l = W2h + WEL;
  ushort_t* W3h = W2l + WEL;    ushort_t* W3l = W3h + WEL;
  ushort_t* Qh = W3l + WEL;     ushort_t* Ql = Qh + EL;
  float* maskF = (float*)W0h;   // 16 KB, alias; valid only after Q-GEMM

  pack_mat<<<dim3(2048), dim3(256), 0, stream>>>(query, X0h, X0l, 0);
  pack_mat<<<dim3(2048), dim3(256), 0, stream>>>(key, X1h, X1l, 0);
  pack_mat<<<dim3(2048), dim3(256), 0, stream>>>(value, X2h, X2l, 0);
  pack_mat<<<dim3(512), dim3(256), 0, stream>>>(Wq, W0h, W0l, 1);
  pack_mat<<<dim3(512), dim3(256), 0, stream>>>(Wk, W1h, W1l, 1);
  pack_mat<<<dim3(512), dim3(256), 0, stream>>>(Wv, W2h, W2l, 1);
  pack_mat<<<dim3(512), dim3(256), 0, stream>>>(Wo, W3h, W3l, 1);

  dim3 gg(HID / 64, MTOT / 128);
  gemm_pack<<<gg, 256, 0, stream>>>(X0h, X0l, W0h, W0l, bq, Qh, Ql, nullptr,
                                    QSCALE, 0);  // Q (pre-scaled, exp2 domain)
  // W0 (Wq packed) is dead from here; reuse its space for the float mask.
  mask_to_float<<<dim3(16), dim3(256), 0, stream>>>(mask, maskF);
  gemm_pack<<<gg, 256, 0, stream>>>(X1h, X1l, W1h, W1l, bk, X0h, X0l, nullptr,
                                    1.0f, 0);    // K
  gemm_pack<<<gg, 256, 0, stream>>>(X2h, X2l, W2h, W2l, bv, X1h, X1l, nullptr,
                                    1.0f, 1);    // V

  attn_kernel<<<dim3(S_LEN / 128, NH, 2), 256, 0, stream>>>(
      Qh, Ql, X0h, X0l, X1h, X1l, maskF, X2h, X2l);

  gemm_pack<<<gg, 256, 0, stream>>>(X2h, X2l, W3h, W3l, bo, nullptr, nullptr,
                                    out, 1.0f, 2);
}

// Round 6
// 405.462 us; speedup vs baseline: 1.2725x; 1.0556x over previous
//
#include <hip/hip_runtime.h>

// ---------------------------------------------------------------------------
// MHA: out = ((softmax(mask((XqWq+bq)(XkWk+bk)^T/8)) (XvWv+bv)) Wo + bo)^T
// B=2, S=2048, HID=1024, H=16, Dh=64.  All fp32 in/out.
// 3-term bf16 hi/lo split MFMA. GEMMs: m97-style LDS-staged K-loop.
// Attention: swapped operands (mfma(K,Q), mfma(V,P)), LDS-staged K/V,
// in-lane softmax + defer-max.
// ---------------------------------------------------------------------------

typedef unsigned short ushort_t;
typedef unsigned long long ull_t;
typedef __attribute__((ext_vector_type(8))) short short8;
typedef __attribute__((ext_vector_type(4))) float f32x4;

#define S_LEN 2048
#define HID 1024
#define NH 16
#define MTOT 4096            // B*S rows
#define KB 128               // HID/8 k8-blocks
#define PERHEAD 131072       // per-(b,h) packed elems (S*64)
#define QSCALE 0.18033688011112042f   // (1/8) * log2(e): softmax in exp2 domain

// RNE fp32 -> bf16 split (hi RNE, lo RNE of residual)
__device__ __forceinline__ void bsplit(float x, ushort_t& h, ushort_t& l) {
  unsigned u = __float_as_uint(x);
  unsigned hr = (u + 0x7fffu + ((u >> 16) & 1u)) >> 16;
  h = (ushort_t)hr;
  float hf = __uint_as_float(hr << 16);
  float r = x - hf;
  unsigned u2 = __float_as_uint(r);
  l = (ushort_t)((u2 + 0x7fffu + ((u2 >> 16) & 1u)) >> 16);
}

// trunc-hi + cvt_pk RNE-lo split of 4 floats -> two u64 (hi-pair, lo-pair)
__device__ __forceinline__ void qsplit4(float v0, float v1, float v2, float v3,
                                        ull_t& hi, ull_t& lo) {
  unsigned u0 = __float_as_uint(v0), u1 = __float_as_uint(v1);
  unsigned u2 = __float_as_uint(v2), u3 = __float_as_uint(v3);
  unsigned h01 = (u0 >> 16) | (u1 & 0xffff0000u);
  unsigned h23 = (u2 >> 16) | (u3 & 0xffff0000u);
  float r0 = v0 - __uint_as_float(u0 & 0xffff0000u);
  float r1 = v1 - __uint_as_float(u1 & 0xffff0000u);
  float r2 = v2 - __uint_as_float(u2 & 0xffff0000u);
  float r3 = v3 - __uint_as_float(u3 & 0xffff0000u);
  unsigned l01, l23;
  asm("v_cvt_pk_bf16_f32 %0, %1, %2" : "=v"(l01) : "v"(r0), "v"(r1));
  asm("v_cvt_pk_bf16_f32 %0, %1, %2" : "=v"(l23) : "v"(r2), "v"(r3));
  hi = (ull_t)h01 | ((ull_t)h23 << 32);
  lo = (ull_t)l01 | ((ull_t)l23 << 32);
}

__device__ __forceinline__ void gload16(const ushort_t* g, ushort_t* l) {
  __builtin_amdgcn_global_load_lds(
      (const __attribute__((address_space(1))) unsigned int*)g,
      (__attribute__((address_space(3))) unsigned int*)l, 16, 0, 0);
}

// ---------------------------------------------------------------------------
__global__ __launch_bounds__(256) void pack_mat(const float* __restrict__ src,
                                                ushort_t* __restrict__ hi,
                                                ushort_t* __restrict__ lo,
                                                int bmode) {
  int tid = blockIdx.x * 256 + threadIdx.x;
  int r = tid & 15;
  int k8 = (tid >> 4) & (KB - 1);
  int o16 = tid >> 11;
  float v[8];
  if (bmode == 0) {
    const float* s = src + (size_t)(o16 * 16 + r) * HID + k8 * 8;
    const f32x4 f0 = *(const f32x4*)s;
    const f32x4 f1 = *(const f32x4*)(s + 4);
#pragma unroll
    for (int j = 0; j < 4; ++j) { v[j] = f0[j]; v[4 + j] = f1[j]; }
  } else {
#pragma unroll
    for (int j = 0; j < 8; ++j)
      v[j] = src[(size_t)(k8 * 8 + j) * HID + o16 * 16 + r];
  }
  short8 H, L;
#pragma unroll
  for (int j = 0; j < 8; ++j) {
    ushort_t h, l;
    bsplit(v[j], h, l);
    H[j] = (short)h;
    L[j] = (short)l;
  }
  *(short8*)(hi + (size_t)tid * 8) = H;
  *(short8*)(lo + (size_t)tid * 8) = L;
}

__global__ __launch_bounds__(256) void mask_to_float(const int* __restrict__ m,
                                                     float* __restrict__ mf) {
  int i = blockIdx.x * 256 + threadIdx.x;
  mf[i] = m[i] ? 0.f : -1e9f;
}

// ---------------------------------------------------------------------------
// gemm_pack: C = A(4096x1024) * B(1024x1024) + bias, 3-term split MFMA.
// m97-style: BM=128 BN=64 BK=32; A/B K-slabs staged to LDS via
// global_load_lds(16B); 2 barriers per K-step; ds_read_b128 fragments.
// 4 waves 2x2 (wave = 64 rows x 32 cols, 4x2 frags of 16x16).
// mode 0: pack (scale*(C+bias)) -> QK layout [b][h][s16][d8][16][8]
// mode 1: pack -> V layout [b][h][d16][s8][16][8]
// mode 2: fp32 store transposed: out[b][n][s]
// ---------------------------------------------------------------------------
__global__ __launch_bounds__(256) void gemm_pack(
    const ushort_t* __restrict__ Ahi, const ushort_t* __restrict__ Alo,
    const ushort_t* __restrict__ Bhi, const ushort_t* __restrict__ Blo,
    const float* __restrict__ bias, ushort_t* __restrict__ Ohi,
    ushort_t* __restrict__ Olo, float* __restrict__ Ofp, float scale,
    int mode) {
  // 32KB: staging slabs during K-loop; lhi/llo during epilogue.
  // sAh = [0,4096)  [m16 8][k8 4][16][8]
  // sAl = [4096,8192)   sBh = [8192,10240)  sBl = [10240,12288)
  __shared__ ushort_t sbuf[16384];
  const int m0 = blockIdx.y * 128;
  const int n0 = blockIdx.x * 64;
  const int lane = threadIdx.x & 63;
  const int wv = threadIdx.x >> 6;
  const int wr = wv >> 1, wc = wv & 1;
  const int l15 = lane & 15, l4 = lane >> 4;

  f32x4 acc[4][2] = {};

  // 6 staging chunks per wave (24 total): Ah 8, Al 8, Bh 4, Bl 4.
  const ushort_t* gsrc[6];
  ushort_t* ldst[6];
  {
    const size_t ab = (size_t)(m0 >> 4) * 16384 + lane * 8;
    const size_t bb = (size_t)(n0 >> 4) * 16384 + lane * 8;
#pragma unroll
    for (int t = 0; t < 6; ++t) {
      int c = t * 4 + wv;
      if (c < 8) {
        gsrc[t] = Ahi + ab + (size_t)c * 16384;
        ldst[t] = &sbuf[c * 512];
      } else if (c < 16) {
        gsrc[t] = Alo + ab + (size_t)(c - 8) * 16384;
        ldst[t] = &sbuf[4096 + (c - 8) * 512];
      } else if (c < 20) {
        gsrc[t] = Bhi + bb + (size_t)(c - 16) * 16384;
        ldst[t] = &sbuf[8192 + (c - 16) * 512];
      } else {
        gsrc[t] = Blo + bb + (size_t)(c - 20) * 16384;
        ldst[t] = &sbuf[10240 + (c - 20) * 512];
      }
    }
  }

  for (int ks = 0; ks < HID / 32; ++ks) {
    __syncthreads();  // previous step's ds_reads consumed
#pragma unroll
    for (int t = 0; t < 6; ++t) gload16(gsrc[t] + ks * 512, ldst[t]);
    asm volatile("s_waitcnt vmcnt(0)" ::: "memory");
    __syncthreads();

    short8 ah[4], al[4], bh[2], bl[2];
#pragma unroll
    for (int mi = 0; mi < 4; ++mi) {
      int e = (wr * 4 + mi) * 512 + l4 * 128 + l15 * 8;
      ah[mi] = *(const short8*)&sbuf[e];
      al[mi] = *(const short8*)&sbuf[4096 + e];
    }
#pragma unroll
    for (int ni = 0; ni < 2; ++ni) {
      int e = (wc * 2 + ni) * 512 + l4 * 128 + l15 * 8;
      bh[ni] = *(const short8*)&sbuf[8192 + e];
      bl[ni] = *(const short8*)&sbuf[10240 + e];
    }
#pragma unroll
    for (int mi = 0; mi < 4; ++mi)
#pragma unroll
      for (int ni = 0; ni < 2; ++ni) {
        acc[mi][ni] = __builtin_amdgcn_mfma_f32_16x16x32_bf16(al[mi], bh[ni], acc[mi][ni], 0, 0, 0);
        acc[mi][ni] = __builtin_amdgcn_mfma_f32_16x16x32_bf16(ah[mi], bl[ni], acc[mi][ni], 0, 0, 0);
        acc[mi][ni] = __builtin_amdgcn_mfma_f32_16x16x32_bf16(ah[mi], bh[ni], acc[mi][ni], 0, 0, 0);
      }
  }

  if (mode < 2) {
    __syncthreads();  // staging reads done before sbuf reuse as lhi/llo
    // lhi = sbuf[0,8192), llo = sbuf[8192,16384)
#pragma unroll
    for (int mi = 0; mi < 4; ++mi)
#pragma unroll
      for (int ni = 0; ni < 2; ++ni) {
        int col = wc * 32 + ni * 16 + l15;  // 0..63 (= d within head)
        float bvv = bias[n0 + col];
#pragma unroll
        for (int i = 0; i < 4; ++i) {
          int row = wr * 64 + mi * 16 + l4 * 4 + i;  // 0..127 (s local)
          float v = (acc[mi][ni][i] + bvv) * scale;
          ushort_t hh, ll;
          bsplit(v, hh, ll);
          int loc = (mode == 0)
                        ? (((row >> 4) * 8 + (col >> 3)) * 128 + (row & 15) * 8 + (col & 7))
                        : (((col >> 4) * 16 + (row >> 3)) * 128 + (col & 15) * 8 + (row & 7));
          sbuf[loc] = hh;
          sbuf[8192 + loc] = ll;
        }
      }
    __syncthreads();
    const int hd = n0 >> 6;              // head (BN=64 == one head)
    const int b_ = m0 >> 11;             // batch
    const int s0 = m0 & (S_LEN - 1);     // seq base
    const size_t hb = (size_t)(b_ * NH + hd) * PERHEAD;
#pragma unroll
    for (int r2 = 0; r2 < 2; ++r2) {
      int t = r2 * 256 + threadIdx.x;
      size_t dst;
      if (mode == 0) {
        int m16loc = (t * 16) >> 10, rem = (t * 16) & 1023;
        dst = hb + (size_t)((s0 >> 4) + m16loc) * 1024 + rem;
      } else {
        int dg = (t * 16) >> 11, rem = (t * 16) & 2047;
        dst = hb + (size_t)dg * 32768 + (size_t)(s0 >> 3) * 128 + rem;
      }
      *(short8*)(Ohi + dst) = *(const short8*)&sbuf[t * 16];
      *(short8*)(Ohi + dst + 8) = *(const short8*)&sbuf[t * 16 + 8];
      *(short8*)(Olo + dst) = *(const short8*)&sbuf[8192 + t * 16];
      *(short8*)(Olo + dst + 8) = *(const short8*)&sbuf[8192 + t * 16 + 8];
    }
  } else {
#pragma unroll
    for (int mi = 0; mi < 4; ++mi)
#pragma unroll
      for (int ni = 0; ni < 2; ++ni) {
        int col = n0 + wc * 32 + ni * 16 + l15;
        float bvv = bias[col];
        int m = m0 + wr * 64 + mi * 16 + l4 * 4;
        int b_ = m >> 11, s = m & (S_LEN - 1);
        f32x4 v = acc[mi][ni];
        v[0] += bvv; v[1] += bvv; v[2] += bvv; v[3] += bvv;
        *(f32x4*)(Ofp + (size_t)(b_ * HID + col) * S_LEN + s) = v;
      }
  }
}

// ---------------------------------------------------------------------------
// Flash attention, swapped operands. Block = (qb, h, b): 128 q-rows, 4 waves
// x 32 q-rows (2 q16-frags each). K/V tiles (64 keys) staged in LDS via
// global_load_lds, shared by all waves. Scores S^T = mfma(K,Q): lane holds
// q = l15, keys = cg*16 + l4*4 + i  -> in-lane softmax + 2 shuffles.
// Defer-max: skip O rescale when no lane's max grew. P -> LDS as b64,
// PV: O^T = mfma(V^T, P).
// ---------------------------------------------------------------------------
__global__ __launch_bounds__(256) void attn_kernel(
    const ushort_t* __restrict__ Qhi, const ushort_t* __restrict__ Qlo,
    const ushort_t* __restrict__ Khi, const ushort_t* __restrict__ Klo,
    const ushort_t* __restrict__ Vhi, const ushort_t* __restrict__ Vlo,
    const float* __restrict__ maskF, ushort_t* __restrict__ Xhi,
    ushort_t* __restrict__ Xlo) {
  __shared__ ushort_t KtH[4096], KtL[4096], VtH[4096], VtL[4096];
  __shared__ ushort_t PH[4][2][1024], PL[4][2][1024];
  const int qb = blockIdx.x, h = blockIdx.y, b = blockIdx.z;
  const int lane = threadIdx.x & 63, wv = threadIdx.x >> 6;
  const int l15 = lane & 15, l4 = lane >> 4;
  const size_t hb = (size_t)(b * NH + h) * PERHEAD;

  // Q fragments resident (as B-operand: col=l15=q, k=d)
  short8 qh[2][2], ql[2][2];
#pragma unroll
  for (int qi = 0; qi < 2; ++qi)
#pragma unroll
    for (int kk = 0; kk < 2; ++kk) {
      size_t o = hb + (size_t)(qb * 8 + wv * 2 + qi) * 1024 + (kk * 4 + l4) * 128 + l15 * 8;
      qh[qi][kk] = *(const short8*)(Qhi + o);
      ql[qi][kk] = *(const short8*)(Qlo + o);
    }

  const float* mrow = maskF + b * S_LEN;
  f32x4 o_acc[2][4] = {};
  float m_r[2] = {-1e30f, -1e30f}, l_r[2] = {0.f, 0.f};

  for (int kt = 0; kt < S_LEN / 64; ++kt) {
    __syncthreads();  // previous tile's compute done before overwrite
    // ---- stage K/V tile (64 keys) into LDS, linear copies ----
#pragma unroll
    for (int c = 0; c < 2; ++c) {
      int chunk = wv * 2 + c;                       // 0..7
      size_t ko = hb + (size_t)kt * 4096 + chunk * 512 + lane * 8;
      gload16(Khi + ko, &KtH[chunk * 512]);
      gload16(Klo + ko, &KtL[chunk * 512]);
      int dg = chunk >> 1, hf = chunk & 1;
      size_t vo = hb + (size_t)dg * 32768 + (size_t)kt * 1024 + hf * 512 + lane * 8;
      gload16(Vhi + vo, &VtH[chunk * 512]);
      gload16(Vlo + vo, &VtL[chunk * 512]);
    }
    f32x4 mf[4];
#pragma unroll
    for (int cg = 0; cg < 4; ++cg)
      mf[cg] = *(const f32x4*)(mrow + kt * 64 + cg * 16 + l4 * 4);
    asm volatile("s_waitcnt vmcnt(0)" ::: "memory");
    __syncthreads();

    // ---- scores S^T = K Q^T (3-term), + mask ----
    f32x4 sc[2][4];
#pragma unroll
    for (int cg = 0; cg < 4; ++cg) {
      short8 kh[2], kl[2];
#pragma unroll
      for (int kk = 0; kk < 2; ++kk) {
        int e = cg * 1024 + (kk * 4 + l4) * 128 + l15 * 8;
        kh[kk] = *(const short8*)&KtH[e];
        kl[kk] = *(const short8*)&KtL[e];
      }
#pragma unroll
      for (int qi = 0; qi < 2; ++qi) {
        f32x4 a = {};
#pragma unroll
        for (int kk = 0; kk < 2; ++kk) {
          a = __builtin_amdgcn_mfma_f32_16x16x32_bf16(kl[kk], qh[qi][kk], a, 0, 0, 0);
          a = __builtin_amdgcn_mfma_f32_16x16x32_bf16(kh[kk], ql[qi][kk], a, 0, 0, 0);
          a = __builtin_amdgcn_mfma_f32_16x16x32_bf16(kh[kk], qh[qi][kk], a, 0, 0, 0);
        }
        a[0] += mf[cg][0]; a[1] += mf[cg][1]; a[2] += mf[cg][2]; a[3] += mf[cg][3];
        sc[qi][cg] = a;
      }
    }

    // ---- online softmax (exp2 domain, defer-max), P -> LDS ----
#pragma unroll
    for (int qi = 0; qi < 2; ++qi) {
      float tm = fmaxf(fmaxf(fmaxf(sc[qi][0][0], sc[qi][0][1]), fmaxf(sc[qi][0][2], sc[qi][0][3])),
                       fmaxf(fmaxf(sc[qi][1][0], sc[qi][1][1]), fmaxf(sc[qi][1][2], sc[qi][1][3])));
      float tm2 = fmaxf(fmaxf(fmaxf(sc[qi][2][0], sc[qi][2][1]), fmaxf(sc[qi][2][2], sc[qi][2][3])),
                        fmaxf(fmaxf(sc[qi][3][0], sc[qi][3][1]), fmaxf(sc[qi][3][2], sc[qi][3][3])));
      tm = fmaxf(tm, tm2);
      tm = fmaxf(tm, __shfl_xor(tm, 16));
      tm = fmaxf(tm, __shfl_xor(tm, 32));
      float mn;
      if (__all(tm <= m_r[qi])) {
        mn = m_r[qi];  // no growth anywhere in the wave: skip rescale
      } else {
        mn = fmaxf(m_r[qi], tm);
        float fs = exp2f(m_r[qi] - mn);
        m_r[qi] = mn;
        l_r[qi] *= fs;
#pragma unroll
        for (int dg = 0; dg < 4; ++dg) o_acc[qi][dg] *= fs;
      }
      float ts = 0.f;
#pragma unroll
      for (int cg = 0; cg < 4; ++cg) {
        float p0 = exp2f(sc[qi][cg][0] - mn);
        float p1 = exp2f(sc[qi][cg][1] - mn);
        float p2 = exp2f(sc[qi][cg][2] - mn);
        float p3 = exp2f(sc[qi][cg][3] - mn);
        ts += (p0 + p1) + (p2 + p3);
        ull_t hi, lo;
        qsplit4(p0, p1, p2, p3, hi, lo);
        int e = (cg * 2 + (l4 >> 1)) * 128 + l15 * 8 + (l4 & 1) * 4;
        *(ull_t*)&PH[wv][qi][e] = hi;
        *(ull_t*)&PL[wv][qi][e] = lo;
      }
      ts += __shfl_xor(ts, 16);
      ts += __shfl_xor(ts, 32);
      l_r[qi] += ts;
    }

    // ---- O^T += V^T P (3-term) ----
#pragma unroll
    for (int kk = 0; kk < 2; ++kk) {
      short8 vh[4], vl[4];
#pragma unroll
      for (int dg = 0; dg < 4; ++dg) {
        int e = dg * 1024 + (kk * 4 + l4) * 128 + l15 * 8;
        vh[dg] = *(const short8*)&VtH[e];
        vl[dg] = *(const short8*)&VtL[e];
      }
#pragma unroll
      for (int qi = 0; qi < 2; ++qi) {
        int pe = (kk * 4 + l4) * 128 + l15 * 8;
        short8 pbh = *(const short8*)&PH[wv][qi][pe];
        short8 pbl = *(const short8*)&PL[wv][qi][pe];
#pragma unroll
        for (int dg = 0; dg < 4; ++dg) {
          o_acc[qi][dg] = __builtin_amdgcn_mfma_f32_16x16x32_bf16(vh[dg], pbl, o_acc[qi][dg], 0, 0, 0);
          o_acc[qi][dg] = __builtin_amdgcn_mfma_f32_16x16x32_bf16(vl[dg], pbh, o_acc[qi][dg], 0, 0, 0);
          o_acc[qi][dg] = __builtin_amdgcn_mfma_f32_16x16x32_bf16(vh[dg], pbh, o_acc[qi][dg], 0, 0, 0);
        }
      }
    }
  }

  // ---- epilogue: x = O/l, direct global store in A-frag layout ----
#pragma unroll
  for (int qi = 0; qi < 2; ++qi) {
    float rl = 1.0f / l_r[qi];
    int m16 = b * 128 + qb * 8 + wv * 2 + qi;
#pragma unroll
    for (int dg = 0; dg < 4; ++dg) {
      float v0 = o_acc[qi][dg][0] * rl;
      float v1 = o_acc[qi][dg][1] * rl;
      float v2 = o_acc[qi][dg][2] * rl;
      float v3 = o_acc[qi][dg][3] * rl;
      ull_t hi, lo;
      qsplit4(v0, v1, v2, v3, hi, lo);
      size_t dst = (size_t)m16 * 16384 + (size_t)(h * 8 + dg * 2 + (l4 >> 1)) * 128 + l15 * 8 + (l4 & 1) * 4;
      *(ull_t*)(Xhi + dst) = hi;
      *(ull_t*)(Xlo + dst) = lo;
    }
  }
}

// ---------------------------------------------------------------------------
extern "C" void kernel_launch(void* const* d_in, const int* in_sizes, int n_in,
                              void* d_out, int out_size, void* d_ws,
                              size_t ws_size, hipStream_t stream) {
  (void)in_sizes; (void)n_in; (void)out_size; (void)ws_size;
  const float* query = (const float*)d_in[0];
  const float* key = (const float*)d_in[1];
  const float* value = (const float*)d_in[2];
  const int* mask = (const int*)d_in[3];
  const float* Wq = (const float*)d_in[4];
  const float* bq = (const float*)d_in[5];
  const float* Wk = (const float*)d_in[6];
  const float* bk = (const float*)d_in[7];
  const float* Wv = (const float*)d_in[8];
  const float* bv = (const float*)d_in[9];
  const float* Wo = (const float*)d_in[10];
  const float* bo = (const float*)d_in[11];
  float* out = (float*)d_out;

  // workspace layout (ushort elems). Total = 40 Mi elems = 80 MiB
  // (identical footprint to the round-2 PASSED layout; maskF aliases W0h,
  // which is dead after the Q-projection GEMM).
  const size_t EL = (size_t)MTOT * HID;  // 4 Mi elems
  const size_t WEL = (size_t)HID * HID;  // 1 Mi elems
  ushort_t* p = (ushort_t*)d_ws;
  ushort_t* X0h = p;            ushort_t* X0l = X0h + EL;
  ushort_t* X1h = X0l + EL;     ushort_t* X1l = X1h + EL;
  ushort_t* X2h = X1l + EL;     ushort_t* X2l = X2h + EL;
  ushort_t* W0h = X2l + EL;     ushort_t* W0l = W0h + WEL;
  ushort_t* W1h = W0l + WEL;    ushort_t* W1l = W1h + WEL;
  ushort_t* W2h = W1l + WEL;    ushort_t* W2l = W2h + WEL;
  ushort_t* W3h = W2l + WEL;    ushort_t* W3l = W3h + WEL;
  ushort_t* Qh = W3l + WEL;     ushort_t* Ql = Qh + EL;
  float* maskF = (float*)W0h;   // 16 KB, alias; valid only after Q-GEMM

  pack_mat<<<dim3(2048), dim3(256), 0, stream>>>(query, X0h, X0l, 0);
  pack_mat<<<dim3(2048), dim3(256), 0, stream>>>(key, X1h, X1l, 0);
  pack_mat<<<dim3(2048), dim3(256), 0, stream>>>(value, X2h, X2l, 0);
  pack_mat<<<dim3(512), dim3(256), 0, stream>>>(Wq, W0h, W0l, 1);
  pack_mat<<<dim3(512), dim3(256), 0, stream>>>(Wk, W1h, W1l, 1);
  pack_mat<<<dim3(512), dim3(256), 0, stream>>>(Wv, W2h, W2l, 1);
  pack_mat<<<dim3(512), dim3(256), 0, stream>>>(Wo, W3h, W3l, 1);

  dim3 gg(HID / 64, MTOT / 128);
  gemm_pack<<<gg, 256, 0, stream>>>(X0h, X0l, W0h, W0l, bq, Qh, Ql, nullptr,
                                    QSCALE, 0);  // Q (pre-scaled, exp2 domain)
  // W0 (Wq packed) is dead from here; reuse its space for the float mask.
  mask_to_float<<<dim3(16), dim3(256), 0, stream>>>(mask, maskF);
  gemm_pack<<<gg, 256, 0, stream>>>(X1h, X1l, W1h, W1l, bk, X0h, X0l, nullptr,
                                    1.0f, 0);    // K
  gemm_pack<<<gg, 256, 0, stream>>>(X2h, X2l, W2h, W2l, bv, X1h, X1l, nullptr,
                                    1.0f, 1);    // V

  attn_kernel<<<dim3(S_LEN / 128, NH, 2), 256, 0, stream>>>(
      Qh, Ql, X0h, X0l, X1h, X1l, maskF, X2h, X2l);

  gemm_pack<<<gg, 256, 0, stream>>>(X2h, X2l, W3h, W3l, bo, nullptr, nullptr,
                                    out, 1.0f, 2);
}

// Round 7
// 402.532 us; speedup vs baseline: 1.2818x; 1.0073x over previous
//
#include <hip/hip_runtime.h>

// ---------------------------------------------------------------------------
// MHA: out = ((softmax(mask((XqWq+bq)(XkWk+bk)^T/8)) (XvWv+bv)) Wo + bo)^T
// B=2, S=2048, HID=1024, H=16, Dh=64.  All fp32 in/out.
// 3-term bf16 hi/lo split MFMA. GEMMs: 2-phase double-buffered LDS staging
// (T3 minimum pipeline). Attention: swapped operands, LDS-staged K/V,
// in-lane softmax + defer-max.
// ---------------------------------------------------------------------------

typedef unsigned short ushort_t;
typedef unsigned long long ull_t;
typedef __attribute__((ext_vector_type(8))) short short8;
typedef __attribute__((ext_vector_type(4))) float f32x4;

#define S_LEN 2048
#define HID 1024
#define NH 16
#define MTOT 4096            // B*S rows
#define KB 128               // HID/8 k8-blocks
#define PERHEAD 131072       // per-(b,h) packed elems (S*64)
#define QSCALE 0.18033688011112042f   // (1/8) * log2(e): softmax in exp2 domain

// RNE fp32 -> bf16 split (hi RNE, lo RNE of residual)
__device__ __forceinline__ void bsplit(float x, ushort_t& h, ushort_t& l) {
  unsigned u = __float_as_uint(x);
  unsigned hr = (u + 0x7fffu + ((u >> 16) & 1u)) >> 16;
  h = (ushort_t)hr;
  float hf = __uint_as_float(hr << 16);
  float r = x - hf;
  unsigned u2 = __float_as_uint(r);
  l = (ushort_t)((u2 + 0x7fffu + ((u2 >> 16) & 1u)) >> 16);
}

// trunc-hi + cvt_pk RNE-lo split of 4 floats -> two u64 (hi-pair, lo-pair)
__device__ __forceinline__ void qsplit4(float v0, float v1, float v2, float v3,
                                        ull_t& hi, ull_t& lo) {
  unsigned u0 = __float_as_uint(v0), u1 = __float_as_uint(v1);
  unsigned u2 = __float_as_uint(v2), u3 = __float_as_uint(v3);
  unsigned h01 = (u0 >> 16) | (u1 & 0xffff0000u);
  unsigned h23 = (u2 >> 16) | (u3 & 0xffff0000u);
  float r0 = v0 - __uint_as_float(u0 & 0xffff0000u);
  float r1 = v1 - __uint_as_float(u1 & 0xffff0000u);
  float r2 = v2 - __uint_as_float(u2 & 0xffff0000u);
  float r3 = v3 - __uint_as_float(u3 & 0xffff0000u);
  unsigned l01, l23;
  asm("v_cvt_pk_bf16_f32 %0, %1, %2" : "=v"(l01) : "v"(r0), "v"(r1));
  asm("v_cvt_pk_bf16_f32 %0, %1, %2" : "=v"(l23) : "v"(r2), "v"(r3));
  hi = (ull_t)h01 | ((ull_t)h23 << 32);
  lo = (ull_t)l01 | ((ull_t)l23 << 32);
}

__device__ __forceinline__ void gload16(const ushort_t* g, ushort_t* l) {
  __builtin_amdgcn_global_load_lds(
      (const __attribute__((address_space(1))) unsigned int*)g,
      (__attribute__((address_space(3))) unsigned int*)l, 16, 0, 0);
}

// ---------------------------------------------------------------------------
__global__ __launch_bounds__(256) void pack_mat(const float* __restrict__ src,
                                                ushort_t* __restrict__ hi,
                                                ushort_t* __restrict__ lo,
                                                int bmode) {
  int tid = blockIdx.x * 256 + threadIdx.x;
  int r = tid & 15;
  int k8 = (tid >> 4) & (KB - 1);
  int o16 = tid >> 11;
  float v[8];
  if (bmode == 0) {
    const float* s = src + (size_t)(o16 * 16 + r) * HID + k8 * 8;
    const f32x4 f0 = *(const f32x4*)s;
    const f32x4 f1 = *(const f32x4*)(s + 4);
#pragma unroll
    for (int j = 0; j < 4; ++j) { v[j] = f0[j]; v[4 + j] = f1[j]; }
  } else {
#pragma unroll
    for (int j = 0; j < 8; ++j)
      v[j] = src[(size_t)(k8 * 8 + j) * HID + o16 * 16 + r];
  }
  short8 H, L;
#pragma unroll
  for (int j = 0; j < 8; ++j) {
    ushort_t h, l;
    bsplit(v[j], h, l);
    H[j] = (short)h;
    L[j] = (short)l;
  }
  *(short8*)(hi + (size_t)tid * 8) = H;
  *(short8*)(lo + (size_t)tid * 8) = L;
}

__global__ __launch_bounds__(256) void mask_to_float(const int* __restrict__ m,
                                                     float* __restrict__ mf) {
  int i = blockIdx.x * 256 + threadIdx.x;
  mf[i] = m[i] ? 0.f : -1e9f;
}

// ---------------------------------------------------------------------------
// gemm_pack: C = A(4096x1024) * B(1024x1024) + bias, 3-term split MFMA.
// BM=128 BN=64 BK=32; 2-phase double-buffered LDS staging: issue next
// K-slab's global_load_lds BEFORE computing current slab, vmcnt(0)+barrier
// at phase end (loads had the whole compute phase to land).
// 4 waves 2x2 (wave = 64 rows x 32 cols, 4x2 frags of 16x16).
// mode 0: pack (scale*(C+bias)) -> QK layout [b][h][s16][d8][16][8]
// mode 1: pack -> V layout [b][h][d16][s8][16][8]
// mode 2: fp32 store transposed: out[b][n][s]
// ---------------------------------------------------------------------------
__global__ __launch_bounds__(256) void gemm_pack(
    const ushort_t* __restrict__ Ahi, const ushort_t* __restrict__ Alo,
    const ushort_t* __restrict__ Bhi, const ushort_t* __restrict__ Blo,
    const float* __restrict__ bias, ushort_t* __restrict__ Ohi,
    ushort_t* __restrict__ Olo, float* __restrict__ Ofp, float scale,
    int mode) {
  // 48KB: two 12288-ushort staging buffers; epilogue reuses [0,16384).
  // Within a buffer: sAh [0,4096) [m16 8][k8 4][16][8], sAl [4096,8192),
  // sBh [8192,10240), sBl [10240,12288).
  __shared__ ushort_t sbuf[24576];
  const int m0 = blockIdx.y * 128;
  const int n0 = blockIdx.x * 64;
  const int lane = threadIdx.x & 63;
  const int wv = threadIdx.x >> 6;
  const int wr = wv >> 1, wc = wv & 1;
  const int l15 = lane & 15, l4 = lane >> 4;

  f32x4 acc[4][2] = {};

  // 6 staging chunks per wave (24 total): Ah 8, Al 8, Bh 4, Bl 4.
  const ushort_t* gsrc[6];
  int loff[6];
  {
    const size_t ab = (size_t)(m0 >> 4) * 16384 + lane * 8;
    const size_t bb = (size_t)(n0 >> 4) * 16384 + lane * 8;
#pragma unroll
    for (int t = 0; t < 6; ++t) {
      int c = t * 4 + wv;
      if (c < 8) {
        gsrc[t] = Ahi + ab + (size_t)c * 16384;
        loff[t] = c * 512;
      } else if (c < 16) {
        gsrc[t] = Alo + ab + (size_t)(c - 8) * 16384;
        loff[t] = 4096 + (c - 8) * 512;
      } else if (c < 20) {
        gsrc[t] = Bhi + bb + (size_t)(c - 16) * 16384;
        loff[t] = 8192 + (c - 16) * 512;
      } else {
        gsrc[t] = Blo + bb + (size_t)(c - 20) * 16384;
        loff[t] = 10240 + (c - 20) * 512;
      }
    }
  }

  // prologue: stage slab 0 into buffer 0
#pragma unroll
  for (int t = 0; t < 6; ++t) gload16(gsrc[t], &sbuf[loff[t]]);
  asm volatile("s_waitcnt vmcnt(0)" ::: "memory");
  __syncthreads();

  int cur = 0;
  for (int ks = 0; ks < HID / 32; ++ks) {
    // issue next slab's loads FIRST (into the other buffer)
    if (ks < HID / 32 - 1) {
#pragma unroll
      for (int t = 0; t < 6; ++t)
        gload16(gsrc[t] + (ks + 1) * 512, &sbuf[(cur ^ 1) * 12288 + loff[t]]);
    }
    const ushort_t* sb = &sbuf[cur * 12288];

    short8 ah[4], al[4], bh[2], bl[2];
#pragma unroll
    for (int mi = 0; mi < 4; ++mi) {
      int e = (wr * 4 + mi) * 512 + l4 * 128 + l15 * 8;
      ah[mi] = *(const short8*)&sb[e];
      al[mi] = *(const short8*)&sb[4096 + e];
    }
#pragma unroll
    for (int ni = 0; ni < 2; ++ni) {
      int e = (wc * 2 + ni) * 512 + l4 * 128 + l15 * 8;
      bh[ni] = *(const short8*)&sb[8192 + e];
      bl[ni] = *(const short8*)&sb[10240 + e];
    }
#pragma unroll
    for (int mi = 0; mi < 4; ++mi)
#pragma unroll
      for (int ni = 0; ni < 2; ++ni) {
        acc[mi][ni] = __builtin_amdgcn_mfma_f32_16x16x32_bf16(al[mi], bh[ni], acc[mi][ni], 0, 0, 0);
        acc[mi][ni] = __builtin_amdgcn_mfma_f32_16x16x32_bf16(ah[mi], bl[ni], acc[mi][ni], 0, 0, 0);
        acc[mi][ni] = __builtin_amdgcn_mfma_f32_16x16x32_bf16(ah[mi], bh[ni], acc[mi][ni], 0, 0, 0);
      }
    // wait for next-slab loads (they had the whole compute phase), then sync
    asm volatile("s_waitcnt vmcnt(0)" ::: "memory");
    __syncthreads();
    cur ^= 1;
  }

  if (mode < 2) {
    // epilogue pack: lhi = sbuf[0,8192), llo = sbuf[8192,16384)
#pragma unroll
    for (int mi = 0; mi < 4; ++mi)
#pragma unroll
      for (int ni = 0; ni < 2; ++ni) {
        int col = wc * 32 + ni * 16 + l15;  // 0..63 (= d within head)
        float bvv = bias[n0 + col];
#pragma unroll
        for (int i = 0; i < 4; ++i) {
          int row = wr * 64 + mi * 16 + l4 * 4 + i;  // 0..127 (s local)
          float v = (acc[mi][ni][i] + bvv) * scale;
          ushort_t hh, ll;
          bsplit(v, hh, ll);
          int loc = (mode == 0)
                        ? (((row >> 4) * 8 + (col >> 3)) * 128 + (row & 15) * 8 + (col & 7))
                        : (((col >> 4) * 16 + (row >> 3)) * 128 + (col & 15) * 8 + (row & 7));
          sbuf[loc] = hh;
          sbuf[8192 + loc] = ll;
        }
      }
    __syncthreads();
    const int hd = n0 >> 6;              // head (BN=64 == one head)
    const int b_ = m0 >> 11;             // batch
    const int s0 = m0 & (S_LEN - 1);     // seq base
    const size_t hb = (size_t)(b_ * NH + hd) * PERHEAD;
#pragma unroll
    for (int r2 = 0; r2 < 2; ++r2) {
      int t = r2 * 256 + threadIdx.x;
      size_t dst;
      if (mode == 0) {
        int m16loc = (t * 16) >> 10, rem = (t * 16) & 1023;
        dst = hb + (size_t)((s0 >> 4) + m16loc) * 1024 + rem;
      } else {
        int dg = (t * 16) >> 11, rem = (t * 16) & 2047;
        dst = hb + (size_t)dg * 32768 + (size_t)(s0 >> 3) * 128 + rem;
      }
      *(short8*)(Ohi + dst) = *(const short8*)&sbuf[t * 16];
      *(short8*)(Ohi + dst + 8) = *(const short8*)&sbuf[t * 16 + 8];
      *(short8*)(Olo + dst) = *(const short8*)&sbuf[8192 + t * 16];
      *(short8*)(Olo + dst + 8) = *(const short8*)&sbuf[8192 + t * 16 + 8];
    }
  } else {
#pragma unroll
    for (int mi = 0; mi < 4; ++mi)
#pragma unroll
      for (int ni = 0; ni < 2; ++ni) {
        int col = n0 + wc * 32 + ni * 16 + l15;
        float bvv = bias[col];
        int m = m0 + wr * 64 + mi * 16 + l4 * 4;
        int b_ = m >> 11, s = m & (S_LEN - 1);
        f32x4 v = acc[mi][ni];
        v[0] += bvv; v[1] += bvv; v[2] += bvv; v[3] += bvv;
        *(f32x4*)(Ofp + (size_t)(b_ * HID + col) * S_LEN + s) = v;
      }
  }
}

// ---------------------------------------------------------------------------
// Flash attention, swapped operands. Block = (qb, h, b): 128 q-rows, 4 waves
// x 32 q-rows (2 q16-frags each). K/V tiles (64 keys) staged in LDS via
// global_load_lds, shared by all waves. Scores S^T = mfma(K,Q): lane holds
// q = l15, keys = cg*16 + l4*4 + i  -> in-lane softmax + 2 shuffles.
// Defer-max: skip O rescale when no lane's max grew. P -> LDS as b64,
// PV: O^T = mfma(V^T, P).
// ---------------------------------------------------------------------------
__global__ __launch_bounds__(256) void attn_kernel(
    const ushort_t* __restrict__ Qhi, const ushort_t* __restrict__ Qlo,
    const ushort_t* __restrict__ Khi, const ushort_t* __restrict__ Klo,
    const ushort_t* __restrict__ Vhi, const ushort_t* __restrict__ Vlo,
    const float* __restrict__ maskF, ushort_t* __restrict__ Xhi,
    ushort_t* __restrict__ Xlo) {
  __shared__ ushort_t KtH[4096], KtL[4096], VtH[4096], VtL[4096];
  __shared__ ushort_t PH[4][2][1024], PL[4][2][1024];
  const int qb = blockIdx.x, h = blockIdx.y, b = blockIdx.z;
  const int lane = threadIdx.x & 63, wv = threadIdx.x >> 6;
  const int l15 = lane & 15, l4 = lane >> 4;
  const size_t hb = (size_t)(b * NH + h) * PERHEAD;

  // Q fragments resident (as B-operand: col=l15=q, k=d)
  short8 qh[2][2], ql[2][2];
#pragma unroll
  for (int qi = 0; qi < 2; ++qi)
#pragma unroll
    for (int kk = 0; kk < 2; ++kk) {
      size_t o = hb + (size_t)(qb * 8 + wv * 2 + qi) * 1024 + (kk * 4 + l4) * 128 + l15 * 8;
      qh[qi][kk] = *(const short8*)(Qhi + o);
      ql[qi][kk] = *(const short8*)(Qlo + o);
    }

  const float* mrow = maskF + b * S_LEN;
  f32x4 o_acc[2][4] = {};
  float m_r[2] = {-1e30f, -1e30f}, l_r[2] = {0.f, 0.f};

  for (int kt = 0; kt < S_LEN / 64; ++kt) {
    __syncthreads();  // previous tile's compute done before overwrite
    // ---- stage K/V tile (64 keys) into LDS, linear copies ----
#pragma unroll
    for (int c = 0; c < 2; ++c) {
      int chunk = wv * 2 + c;                       // 0..7
      size_t ko = hb + (size_t)kt * 4096 + chunk * 512 + lane * 8;
      gload16(Khi + ko, &KtH[chunk * 512]);
      gload16(Klo + ko, &KtL[chunk * 512]);
      int dg = chunk >> 1, hf = chunk & 1;
      size_t vo = hb + (size_t)dg * 32768 + (size_t)kt * 1024 + hf * 512 + lane * 8;
      gload16(Vhi + vo, &VtH[chunk * 512]);
      gload16(Vlo + vo, &VtL[chunk * 512]);
    }
    f32x4 mf[4];
#pragma unroll
    for (int cg = 0; cg < 4; ++cg)
      mf[cg] = *(const f32x4*)(mrow + kt * 64 + cg * 16 + l4 * 4);
    asm volatile("s_waitcnt vmcnt(0)" ::: "memory");
    __syncthreads();

    // ---- scores S^T = K Q^T (3-term), + mask ----
    f32x4 sc[2][4];
#pragma unroll
    for (int cg = 0; cg < 4; ++cg) {
      short8 kh[2], kl[2];
#pragma unroll
      for (int kk = 0; kk < 2; ++kk) {
        int e = cg * 1024 + (kk * 4 + l4) * 128 + l15 * 8;
        kh[kk] = *(const short8*)&KtH[e];
        kl[kk] = *(const short8*)&KtL[e];
      }
#pragma unroll
      for (int qi = 0; qi < 2; ++qi) {
        f32x4 a = {};
#pragma unroll
        for (int kk = 0; kk < 2; ++kk) {
          a = __builtin_amdgcn_mfma_f32_16x16x32_bf16(kl[kk], qh[qi][kk], a, 0, 0, 0);
          a = __builtin_amdgcn_mfma_f32_16x16x32_bf16(kh[kk], ql[qi][kk], a, 0, 0, 0);
          a = __builtin_amdgcn_mfma_f32_16x16x32_bf16(kh[kk], qh[qi][kk], a, 0, 0, 0);
        }
        a[0] += mf[cg][0]; a[1] += mf[cg][1]; a[2] += mf[cg][2]; a[3] += mf[cg][3];
        sc[qi][cg] = a;
      }
    }

    // ---- online softmax (exp2 domain, defer-max), P -> LDS ----
#pragma unroll
    for (int qi = 0; qi < 2; ++qi) {
      float tm = fmaxf(fmaxf(fmaxf(sc[qi][0][0], sc[qi][0][1]), fmaxf(sc[qi][0][2], sc[qi][0][3])),
                       fmaxf(fmaxf(sc[qi][1][0], sc[qi][1][1]), fmaxf(sc[qi][1][2], sc[qi][1][3])));
      float tm2 = fmaxf(fmaxf(fmaxf(sc[qi][2][0], sc[qi][2][1]), fmaxf(sc[qi][2][2], sc[qi][2][3])),
                        fmaxf(fmaxf(sc[qi][3][0], sc[qi][3][1]), fmaxf(sc[qi][3][2], sc[qi][3][3])));
      tm = fmaxf(tm, tm2);
      tm = fmaxf(tm, __shfl_xor(tm, 16));
      tm = fmaxf(tm, __shfl_xor(tm, 32));
      float mn;
      if (__all(tm <= m_r[qi])) {
        mn = m_r[qi];  // no growth anywhere in the wave: skip rescale
      } else {
        mn = fmaxf(m_r[qi], tm);
        float fs = exp2f(m_r[qi] - mn);
        m_r[qi] = mn;
        l_r[qi] *= fs;
#pragma unroll
        for (int dg = 0; dg < 4; ++dg) o_acc[qi][dg] *= fs;
      }
      float ts = 0.f;
#pragma unroll
      for (int cg = 0; cg < 4; ++cg) {
        float p0 = exp2f(sc[qi][cg][0] - mn);
        float p1 = exp2f(sc[qi][cg][1] - mn);
        float p2 = exp2f(sc[qi][cg][2] - mn);
        float p3 = exp2f(sc[qi][cg][3] - mn);
        ts += (p0 + p1) + (p2 + p3);
        ull_t hi, lo;
        qsplit4(p0, p1, p2, p3, hi, lo);
        int e = (cg * 2 + (l4 >> 1)) * 128 + l15 * 8 + (l4 & 1) * 4;
        *(ull_t*)&PH[wv][qi][e] = hi;
        *(ull_t*)&PL[wv][qi][e] = lo;
      }
      ts += __shfl_xor(ts, 16);
      ts += __shfl_xor(ts, 32);
      l_r[qi] += ts;
    }

    // ---- O^T += V^T P (3-term) ----
#pragma unroll
    for (int kk = 0; kk < 2; ++kk) {
      short8 vh[4], vl[4];
#pragma unroll
      for (int dg = 0; dg < 4; ++dg) {
        int e = dg * 1024 + (kk * 4 + l4) * 128 + l15 * 8;
        vh[dg] = *(const short8*)&VtH[e];
        vl[dg] = *(const short8*)&VtL[e];
      }
#pragma unroll
      for (int qi = 0; qi < 2; ++qi) {
        int pe = (kk * 4 + l4) * 128 + l15 * 8;
        short8 pbh = *(const short8*)&PH[wv][qi][pe];
        short8 pbl = *(const short8*)&PL[wv][qi][pe];
#pragma unroll
        for (int dg = 0; dg < 4; ++dg) {
          o_acc[qi][dg] = __builtin_amdgcn_mfma_f32_16x16x32_bf16(vh[dg], pbl, o_acc[qi][dg], 0, 0, 0);
          o_acc[qi][dg] = __builtin_amdgcn_mfma_f32_16x16x32_bf16(vl[dg], pbh, o_acc[qi][dg], 0, 0, 0);
          o_acc[qi][dg] = __builtin_amdgcn_mfma_f32_16x16x32_bf16(vh[dg], pbh, o_acc[qi][dg], 0, 0, 0);
        }
      }
    }
  }

  // ---- epilogue: x = O/l, direct global store in A-frag layout ----
#pragma unroll
  for (int qi = 0; qi < 2; ++qi) {
    float rl = 1.0f / l_r[qi];
    int m16 = b * 128 + qb * 8 + wv * 2 + qi;
#pragma unroll
    for (int dg = 0; dg < 4; ++dg) {
      float v0 = o_acc[qi][dg][0] * rl;
      float v1 = o_acc[qi][dg][1] * rl;
      float v2 = o_acc[qi][dg][2] * rl;
      float v3 = o_acc[qi][dg][3] * rl;
      ull_t hi, lo;
      qsplit4(v0, v1, v2, v3, hi, lo);
      size_t dst = (size_t)m16 * 16384 + (size_t)(h * 8 + dg * 2 + (l4 >> 1)) * 128 + l15 * 8 + (l4 & 1) * 4;
      *(ull_t*)(Xhi + dst) = hi;
      *(ull_t*)(Xlo + dst) = lo;
    }
  }
}

// ---------------------------------------------------------------------------
extern "C" void kernel_launch(void* const* d_in, const int* in_sizes, int n_in,
                              void* d_out, int out_size, void* d_ws,
                              size_t ws_size, hipStream_t stream) {
  (void)in_sizes; (void)n_in; (void)out_size; (void)ws_size;
  const float* query = (const float*)d_in[0];
  const float* key = (const float*)d_in[1];
  const float* value = (const float*)d_in[2];
  const int* mask = (const int*)d_in[3];
  const float* Wq = (const float*)d_in[4];
  const float* bq = (const float*)d_in[5];
  const float* Wk = (const float*)d_in[6];
  const float* bk = (const float*)d_in[7];
  const float* Wv = (const float*)d_in[8];
  const float* bv = (const float*)d_in[9];
  const float* Wo = (const float*)d_in[10];
  const float* bo = (const float*)d_in[11];
  float* out = (float*)d_out;

  // workspace layout (ushort elems). Total = 40 Mi elems = 80 MiB
  // (identical footprint to the round-2 PASSED layout; maskF aliases W0h,
  // which is dead after the Q-projection GEMM).
  const size_t EL = (size_t)MTOT * HID;  // 4 Mi elems
  const size_t WEL = (size_t)HID * HID;  // 1 Mi elems
  ushort_t* p = (ushort_t*)d_ws;
  ushort_t* X0h = p;            ushort_t* X0l = X0h + EL;
  ushort_t* X1h = X0l + EL;     ushort_t* X1l = X1h + EL;
  ushort_t* X2h = X1l + EL;     ushort_t* X2l = X2h + EL;
  ushort_t* W0h = X2l + EL;     ushort_t* W0l = W0h + WEL;
  ushort_t* W1h = W0l + WEL;    ushort_t* W1l = W1h + WEL;
  ushort_t* W2h = W1l + WEL;    ushort_t* W2l = W2h + WEL;
  ushort_t* W3h = W2l + WEL;    ushort_t* W3l = W3h + WEL;
  ushort_t* Qh = W3l + WEL;     ushort_t* Ql = Qh + EL;
  float* maskF = (float*)W0h;   // 16 KB, alias; valid only after Q-GEMM

  pack_mat<<<dim3(2048), dim3(256), 0, stream>>>(query, X0h, X0l, 0);
  pack_mat<<<dim3(2048), dim3(256), 0, stream>>>(key, X1h, X1l, 0);
  pack_mat<<<dim3(2048), dim3(256), 0, stream>>>(value, X2h, X2l, 0);
  pack_mat<<<dim3(512), dim3(256), 0, stream>>>(Wq, W0h, W0l, 1);
  pack_mat<<<dim3(512), dim3(256), 0, stream>>>(Wk, W1h, W1l, 1);
  pack_mat<<<dim3(512), dim3(256), 0, stream>>>(Wv, W2h, W2l, 1);
  pack_mat<<<dim3(512), dim3(256), 0, stream>>>(Wo, W3h, W3l, 1);

  dim3 gg(HID / 64, MTOT / 128);
  gemm_pack<<<gg, 256, 0, stream>>>(X0h, X0l, W0h, W0l, bq, Qh, Ql, nullptr,
                                    QSCALE, 0);  // Q (pre-scaled, exp2 domain)
  // W0 (Wq packed) is dead from here; reuse its space for the float mask.
  mask_to_float<<<dim3(16), dim3(256), 0, stream>>>(mask, maskF);
  gemm_pack<<<gg, 256, 0, stream>>>(X1h, X1l, W1h, W1l, bk, X0h, X0l, nullptr,
                                    1.0f, 0);    // K
  gemm_pack<<<gg, 256, 0, stream>>>(X2h, X2l, W2h, W2l, bv, X1h, X1l, nullptr,
                                    1.0f, 1);    // V

  attn_kernel<<<dim3(S_LEN / 128, NH, 2), 256, 0, stream>>>(
      Qh, Ql, X0h, X0l, X1h, X1l, maskF, X2h, X2l);

  gemm_pack<<<gg, 256, 0, stream>>>(X2h, X2l, W3h, W3l, bo, nullptr, nullptr,
                                    out, 1.0f, 2);
}

// Round 8
// 389.429 us; speedup vs baseline: 1.3249x; 1.0336x over previous
//
#include <hip/hip_runtime.h>

// ---------------------------------------------------------------------------
// MHA: out = ((softmax(mask((XqWq+bq)(XkWk+bk)^T/8)) (XvWv+bv)) Wo + bo)^T
// B=2, S=2048, HID=1024, H=16, Dh=64.  All fp32 in/out.
// 3-term bf16 hi/lo split MFMA. GEMMs: 2-phase double-buffered LDS staging +
// XCD-chunked block swizzle (each XCD owns 4 m-tiles x all n -> L2-resident
// operands). Attention: swapped operands, LDS-staged K/V, XCD swizzle
// co-locating same-(b,h) blocks so K/V re-reads hit the XCD's L2.
// ---------------------------------------------------------------------------

typedef unsigned short ushort_t;
typedef unsigned long long ull_t;
typedef __attribute__((ext_vector_type(8))) short short8;
typedef __attribute__((ext_vector_type(4))) float f32x4;

#define S_LEN 2048
#define HID 1024
#define NH 16
#define MTOT 4096            // B*S rows
#define KB 128               // HID/8 k8-blocks
#define PERHEAD 131072       // per-(b,h) packed elems (S*64)
#define QSCALE 0.18033688011112042f   // (1/8) * log2(e): softmax in exp2 domain

// RNE fp32 -> bf16 split (hi RNE, lo RNE of residual)
__device__ __forceinline__ void bsplit(float x, ushort_t& h, ushort_t& l) {
  unsigned u = __float_as_uint(x);
  unsigned hr = (u + 0x7fffu + ((u >> 16) & 1u)) >> 16;
  h = (ushort_t)hr;
  float hf = __uint_as_float(hr << 16);
  float r = x - hf;
  unsigned u2 = __float_as_uint(r);
  l = (ushort_t)((u2 + 0x7fffu + ((u2 >> 16) & 1u)) >> 16);
}

// trunc-hi + cvt_pk RNE-lo split of 4 floats -> two u64 (hi-pair, lo-pair)
__device__ __forceinline__ void qsplit4(float v0, float v1, float v2, float v3,
                                        ull_t& hi, ull_t& lo) {
  unsigned u0 = __float_as_uint(v0), u1 = __float_as_uint(v1);
  unsigned u2 = __float_as_uint(v2), u3 = __float_as_uint(v3);
  unsigned h01 = (u0 >> 16) | (u1 & 0xffff0000u);
  unsigned h23 = (u2 >> 16) | (u3 & 0xffff0000u);
  float r0 = v0 - __uint_as_float(u0 & 0xffff0000u);
  float r1 = v1 - __uint_as_float(u1 & 0xffff0000u);
  float r2 = v2 - __uint_as_float(u2 & 0xffff0000u);
  float r3 = v3 - __uint_as_float(u3 & 0xffff0000u);
  unsigned l01, l23;
  asm("v_cvt_pk_bf16_f32 %0, %1, %2" : "=v"(l01) : "v"(r0), "v"(r1));
  asm("v_cvt_pk_bf16_f32 %0, %1, %2" : "=v"(l23) : "v"(r2), "v"(r3));
  hi = (ull_t)h01 | ((ull_t)h23 << 32);
  lo = (ull_t)l01 | ((ull_t)l23 << 32);
}

__device__ __forceinline__ void gload16(const ushort_t* g, ushort_t* l) {
  __builtin_amdgcn_global_load_lds(
      (const __attribute__((address_space(1))) unsigned int*)g,
      (__attribute__((address_space(3))) unsigned int*)l, 16, 0, 0);
}

// ---------------------------------------------------------------------------
__global__ __launch_bounds__(256) void pack_mat(const float* __restrict__ src,
                                                ushort_t* __restrict__ hi,
                                                ushort_t* __restrict__ lo,
                                                int bmode) {
  int tid = blockIdx.x * 256 + threadIdx.x;
  int r = tid & 15;
  int k8 = (tid >> 4) & (KB - 1);
  int o16 = tid >> 11;
  float v[8];
  if (bmode == 0) {
    const float* s = src + (size_t)(o16 * 16 + r) * HID + k8 * 8;
    const f32x4 f0 = *(const f32x4*)s;
    const f32x4 f1 = *(const f32x4*)(s + 4);
#pragma unroll
    for (int j = 0; j < 4; ++j) { v[j] = f0[j]; v[4 + j] = f1[j]; }
  } else {
#pragma unroll
    for (int j = 0; j < 8; ++j)
      v[j] = src[(size_t)(k8 * 8 + j) * HID + o16 * 16 + r];
  }
  short8 H, L;
#pragma unroll
  for (int j = 0; j < 8; ++j) {
    ushort_t h, l;
    bsplit(v[j], h, l);
    H[j] = (short)h;
    L[j] = (short)l;
  }
  *(short8*)(hi + (size_t)tid * 8) = H;
  *(short8*)(lo + (size_t)tid * 8) = L;
}

__global__ __launch_bounds__(256) void mask_to_float(const int* __restrict__ m,
                                                     float* __restrict__ mf) {
  int i = blockIdx.x * 256 + threadIdx.x;
  mf[i] = m[i] ? 0.f : -1e9f;
}

// ---------------------------------------------------------------------------
// gemm_pack: C = A(4096x1024) * B(1024x1024) + bias, 3-term split MFMA.
// BM=128 BN=64 BK=32; 2-phase double-buffered LDS staging. 1-D grid of 512
// with XCD-chunked swizzle: xcd = L&7 owns m-tiles [4*xcd, 4*xcd+4) x all 16
// n-tiles -> per-XCD K-step working set ~192 KB, L2-resident.
// 4 waves 2x2 (wave = 64 rows x 32 cols, 4x2 frags of 16x16).
// mode 0: pack (scale*(C+bias)) -> QK layout [b][h][s16][d8][16][8]
// mode 1: pack -> V layout [b][h][d16][s8][16][8]
// mode 2: fp32 store transposed: out[b][n][s]
// ---------------------------------------------------------------------------
__global__ __launch_bounds__(256) void gemm_pack(
    const ushort_t* __restrict__ Ahi, const ushort_t* __restrict__ Alo,
    const ushort_t* __restrict__ Bhi, const ushort_t* __restrict__ Blo,
    const float* __restrict__ bias, ushort_t* __restrict__ Ohi,
    ushort_t* __restrict__ Olo, float* __restrict__ Ofp, float scale,
    int mode) {
  __shared__ ushort_t sbuf[24576];
  // XCD-chunked swizzle (512 blocks, 8 XCDs round-robin by blockIdx)
  const int L = blockIdx.x;
  const int xcd = L & 7, slot = L >> 3;       // 64 blocks per XCD
  const int mt = xcd * 4 + (slot >> 4);       // 0..31
  const int nt = slot & 15;                   // 0..15
  const int m0 = mt * 128;
  const int n0 = nt * 64;
  const int lane = threadIdx.x & 63;
  const int wv = threadIdx.x >> 6;
  const int wr = wv >> 1, wc = wv & 1;
  const int l15 = lane & 15, l4 = lane >> 4;

  f32x4 acc[4][2] = {};

  // 6 staging chunks per wave (24 total): Ah 8, Al 8, Bh 4, Bl 4.
  const ushort_t* gsrc[6];
  int loff[6];
  {
    const size_t ab = (size_t)(m0 >> 4) * 16384 + lane * 8;
    const size_t bb = (size_t)(n0 >> 4) * 16384 + lane * 8;
#pragma unroll
    for (int t = 0; t < 6; ++t) {
      int c = t * 4 + wv;
      if (c < 8) {
        gsrc[t] = Ahi + ab + (size_t)c * 16384;
        loff[t] = c * 512;
      } else if (c < 16) {
        gsrc[t] = Alo + ab + (size_t)(c - 8) * 16384;
        loff[t] = 4096 + (c - 8) * 512;
      } else if (c < 20) {
        gsrc[t] = Bhi + bb + (size_t)(c - 16) * 16384;
        loff[t] = 8192 + (c - 16) * 512;
      } else {
        gsrc[t] = Blo + bb + (size_t)(c - 20) * 16384;
        loff[t] = 10240 + (c - 20) * 512;
      }
    }
  }

  // prologue: stage slab 0 into buffer 0
#pragma unroll
  for (int t = 0; t < 6; ++t) gload16(gsrc[t], &sbuf[loff[t]]);
  asm volatile("s_waitcnt vmcnt(0)" ::: "memory");
  __syncthreads();

  int cur = 0;
  for (int ks = 0; ks < HID / 32; ++ks) {
    // issue next slab's loads FIRST (into the other buffer)
    if (ks < HID / 32 - 1) {
#pragma unroll
      for (int t = 0; t < 6; ++t)
        gload16(gsrc[t] + (ks + 1) * 512, &sbuf[(cur ^ 1) * 12288 + loff[t]]);
    }
    const ushort_t* sb = &sbuf[cur * 12288];

    short8 ah[4], al[4], bh[2], bl[2];
#pragma unroll
    for (int mi = 0; mi < 4; ++mi) {
      int e = (wr * 4 + mi) * 512 + l4 * 128 + l15 * 8;
      ah[mi] = *(const short8*)&sb[e];
      al[mi] = *(const short8*)&sb[4096 + e];
    }
#pragma unroll
    for (int ni = 0; ni < 2; ++ni) {
      int e = (wc * 2 + ni) * 512 + l4 * 128 + l15 * 8;
      bh[ni] = *(const short8*)&sb[8192 + e];
      bl[ni] = *(const short8*)&sb[10240 + e];
    }
#pragma unroll
    for (int mi = 0; mi < 4; ++mi)
#pragma unroll
      for (int ni = 0; ni < 2; ++ni) {
        acc[mi][ni] = __builtin_amdgcn_mfma_f32_16x16x32_bf16(al[mi], bh[ni], acc[mi][ni], 0, 0, 0);
        acc[mi][ni] = __builtin_amdgcn_mfma_f32_16x16x32_bf16(ah[mi], bl[ni], acc[mi][ni], 0, 0, 0);
        acc[mi][ni] = __builtin_amdgcn_mfma_f32_16x16x32_bf16(ah[mi], bh[ni], acc[mi][ni], 0, 0, 0);
      }
    asm volatile("s_waitcnt vmcnt(0)" ::: "memory");
    __syncthreads();
    cur ^= 1;
  }

  if (mode < 2) {
    // epilogue pack: lhi = sbuf[0,8192), llo = sbuf[8192,16384)
#pragma unroll
    for (int mi = 0; mi < 4; ++mi)
#pragma unroll
      for (int ni = 0; ni < 2; ++ni) {
        int col = wc * 32 + ni * 16 + l15;  // 0..63 (= d within head)
        float bvv = bias[n0 + col];
#pragma unroll
        for (int i = 0; i < 4; ++i) {
          int row = wr * 64 + mi * 16 + l4 * 4 + i;  // 0..127 (s local)
          float v = (acc[mi][ni][i] + bvv) * scale;
          ushort_t hh, ll;
          bsplit(v, hh, ll);
          int loc = (mode == 0)
                        ? (((row >> 4) * 8 + (col >> 3)) * 128 + (row & 15) * 8 + (col & 7))
                        : (((col >> 4) * 16 + (row >> 3)) * 128 + (col & 15) * 8 + (row & 7));
          sbuf[loc] = hh;
          sbuf[8192 + loc] = ll;
        }
      }
    __syncthreads();
    const int hd = n0 >> 6;              // head (BN=64 == one head)
    const int b_ = m0 >> 11;             // batch
    const int s0 = m0 & (S_LEN - 1);     // seq base
    const size_t hb = (size_t)(b_ * NH + hd) * PERHEAD;
#pragma unroll
    for (int r2 = 0; r2 < 2; ++r2) {
      int t = r2 * 256 + threadIdx.x;
      size_t dst;
      if (mode == 0) {
        int m16loc = (t * 16) >> 10, rem = (t * 16) & 1023;
        dst = hb + (size_t)((s0 >> 4) + m16loc) * 1024 + rem;
      } else {
        int dg = (t * 16) >> 11, rem = (t * 16) & 2047;
        dst = hb + (size_t)dg * 32768 + (size_t)(s0 >> 3) * 128 + rem;
      }
      *(short8*)(Ohi + dst) = *(const short8*)&sbuf[t * 16];
      *(short8*)(Ohi + dst + 8) = *(const short8*)&sbuf[t * 16 + 8];
      *(short8*)(Olo + dst) = *(const short8*)&sbuf[8192 + t * 16];
      *(short8*)(Olo + dst + 8) = *(const short8*)&sbuf[8192 + t * 16 + 8];
    }
  } else {
#pragma unroll
    for (int mi = 0; mi < 4; ++mi)
#pragma unroll
      for (int ni = 0; ni < 2; ++ni) {
        int col = n0 + wc * 32 + ni * 16 + l15;
        float bvv = bias[col];
        int m = m0 + wr * 64 + mi * 16 + l4 * 4;
        int b_ = m >> 11, s = m & (S_LEN - 1);
        f32x4 v = acc[mi][ni];
        v[0] += bvv; v[1] += bvv; v[2] += bvv; v[3] += bvv;
        *(f32x4*)(Ofp + (size_t)(b_ * HID + col) * S_LEN + s) = v;
      }
  }
}

// ---------------------------------------------------------------------------
// Flash attention, swapped operands. 1-D grid 512, XCD swizzle: each XCD owns
// 4 (b,h) combos x all 16 q-blocks -> K/V (4 MB) L2-resident, 16x re-reads
// become L2 hits. Block: 128 q-rows, 4 waves x 32 q-rows. K/V tiles staged
// in LDS via global_load_lds, shared by all waves. Scores S^T = mfma(K,Q):
// in-lane softmax + 2 shuffles; defer-max; P -> LDS b64; O^T = mfma(V^T,P).
// ---------------------------------------------------------------------------
__global__ __launch_bounds__(256) void attn_kernel(
    const ushort_t* __restrict__ Qhi, const ushort_t* __restrict__ Qlo,
    const ushort_t* __restrict__ Khi, const ushort_t* __restrict__ Klo,
    const ushort_t* __restrict__ Vhi, const ushort_t* __restrict__ Vlo,
    const float* __restrict__ maskF, ushort_t* __restrict__ Xhi,
    ushort_t* __restrict__ Xlo) {
  __shared__ ushort_t KtH[4096], KtL[4096], VtH[4096], VtL[4096];
  __shared__ ushort_t PH[4][2][1024], PL[4][2][1024];
  const int L = blockIdx.x;
  const int xcd = L & 7, slot = L >> 3;        // 64 blocks per XCD
  const int combo = xcd * 4 + (slot >> 4);     // 0..31 (b,h)
  const int qb = slot & 15;
  const int b = combo >> 4, h = combo & 15;
  const int lane = threadIdx.x & 63, wv = threadIdx.x >> 6;
  const int l15 = lane & 15, l4 = lane >> 4;
  const size_t hb = (size_t)(b * NH + h) * PERHEAD;

  // Q fragments resident (as B-operand: col=l15=q, k=d)
  short8 qh[2][2], ql[2][2];
#pragma unroll
  for (int qi = 0; qi < 2; ++qi)
#pragma unroll
    for (int kk = 0; kk < 2; ++kk) {
      size_t o = hb + (size_t)(qb * 8 + wv * 2 + qi) * 1024 + (kk * 4 + l4) * 128 + l15 * 8;
      qh[qi][kk] = *(const short8*)(Qhi + o);
      ql[qi][kk] = *(const short8*)(Qlo + o);
    }

  const float* mrow = maskF + b * S_LEN;
  f32x4 o_acc[2][4] = {};
  float m_r[2] = {-1e30f, -1e30f}, l_r[2] = {0.f, 0.f};

  for (int kt = 0; kt < S_LEN / 64; ++kt) {
    __syncthreads();  // previous tile's compute done before overwrite
    // ---- stage K/V tile (64 keys) into LDS, linear copies ----
#pragma unroll
    for (int c = 0; c < 2; ++c) {
      int chunk = wv * 2 + c;                       // 0..7
      size_t ko = hb + (size_t)kt * 4096 + chunk * 512 + lane * 8;
      gload16(Khi + ko, &KtH[chunk * 512]);
      gload16(Klo + ko, &KtL[chunk * 512]);
      int dg = chunk >> 1, hf = chunk & 1;
      size_t vo = hb + (size_t)dg * 32768 + (size_t)kt * 1024 + hf * 512 + lane * 8;
      gload16(Vhi + vo, &VtH[chunk * 512]);
      gload16(Vlo + vo, &VtL[chunk * 512]);
    }
    f32x4 mf[4];
#pragma unroll
    for (int cg = 0; cg < 4; ++cg)
      mf[cg] = *(const f32x4*)(mrow + kt * 64 + cg * 16 + l4 * 4);
    asm volatile("s_waitcnt vmcnt(0)" ::: "memory");
    __syncthreads();

    // ---- scores S^T = K Q^T (3-term), + mask ----
    f32x4 sc[2][4];
#pragma unroll
    for (int cg = 0; cg < 4; ++cg) {
      short8 kh[2], kl[2];
#pragma unroll
      for (int kk = 0; kk < 2; ++kk) {
        int e = cg * 1024 + (kk * 4 + l4) * 128 + l15 * 8;
        kh[kk] = *(const short8*)&KtH[e];
        kl[kk] = *(const short8*)&KtL[e];
      }
#pragma unroll
      for (int qi = 0; qi < 2; ++qi) {
        f32x4 a = {};
#pragma unroll
        for (int kk = 0; kk < 2; ++kk) {
          a = __builtin_amdgcn_mfma_f32_16x16x32_bf16(kl[kk], qh[qi][kk], a, 0, 0, 0);
          a = __builtin_amdgcn_mfma_f32_16x16x32_bf16(kh[kk], ql[qi][kk], a, 0, 0, 0);
          a = __builtin_amdgcn_mfma_f32_16x16x32_bf16(kh[kk], qh[qi][kk], a, 0, 0, 0);
        }
        a[0] += mf[cg][0]; a[1] += mf[cg][1]; a[2] += mf[cg][2]; a[3] += mf[cg][3];
        sc[qi][cg] = a;
      }
    }

    // ---- online softmax (exp2 domain, defer-max), P -> LDS ----
#pragma unroll
    for (int qi = 0; qi < 2; ++qi) {
      float tm = fmaxf(fmaxf(fmaxf(sc[qi][0][0], sc[qi][0][1]), fmaxf(sc[qi][0][2], sc[qi][0][3])),
                       fmaxf(fmaxf(sc[qi][1][0], sc[qi][1][1]), fmaxf(sc[qi][1][2], sc[qi][1][3])));
      float tm2 = fmaxf(fmaxf(fmaxf(sc[qi][2][0], sc[qi][2][1]), fmaxf(sc[qi][2][2], sc[qi][2][3])),
                        fmaxf(fmaxf(sc[qi][3][0], sc[qi][3][1]), fmaxf(sc[qi][3][2], sc[qi][3][3])));
      tm = fmaxf(tm, tm2);
      tm = fmaxf(tm, __shfl_xor(tm, 16));
      tm = fmaxf(tm, __shfl_xor(tm, 32));
      float mn;
      if (__all(tm <= m_r[qi])) {
        mn = m_r[qi];  // no growth anywhere in the wave: skip rescale
      } else {
        mn = fmaxf(m_r[qi], tm);
        float fs = exp2f(m_r[qi] - mn);
        m_r[qi] = mn;
        l_r[qi] *= fs;
#pragma unroll
        for (int dg = 0; dg < 4; ++dg) o_acc[qi][dg] *= fs;
      }
      float ts = 0.f;
#pragma unroll
      for (int cg = 0; cg < 4; ++cg) {
        float p0 = exp2f(sc[qi][cg][0] - mn);
        float p1 = exp2f(sc[qi][cg][1] - mn);
        float p2 = exp2f(sc[qi][cg][2] - mn);
        float p3 = exp2f(sc[qi][cg][3] - mn);
        ts += (p0 + p1) + (p2 + p3);
        ull_t hi, lo;
        qsplit4(p0, p1, p2, p3, hi, lo);
        int e = (cg * 2 + (l4 >> 1)) * 128 + l15 * 8 + (l4 & 1) * 4;
        *(ull_t*)&PH[wv][qi][e] = hi;
        *(ull_t*)&PL[wv][qi][e] = lo;
      }
      ts += __shfl_xor(ts, 16);
      ts += __shfl_xor(ts, 32);
      l_r[qi] += ts;
    }

    // ---- O^T += V^T P (3-term) ----
#pragma unroll
    for (int kk = 0; kk < 2; ++kk) {
      short8 vh[4], vl[4];
#pragma unroll
      for (int dg = 0; dg < 4; ++dg) {
        int e = dg * 1024 + (kk * 4 + l4) * 128 + l15 * 8;
        vh[dg] = *(const short8*)&VtH[e];
        vl[dg] = *(const short8*)&VtL[e];
      }
#pragma unroll
      for (int qi = 0; qi < 2; ++qi) {
        int pe = (kk * 4 + l4) * 128 + l15 * 8;
        short8 pbh = *(const short8*)&PH[wv][qi][pe];
        short8 pbl = *(const short8*)&PL[wv][qi][pe];
#pragma unroll
        for (int dg = 0; dg < 4; ++dg) {
          o_acc[qi][dg] = __builtin_amdgcn_mfma_f32_16x16x32_bf16(vh[dg], pbl, o_acc[qi][dg], 0, 0, 0);
          o_acc[qi][dg] = __builtin_amdgcn_mfma_f32_16x16x32_bf16(vl[dg], pbh, o_acc[qi][dg], 0, 0, 0);
          o_acc[qi][dg] = __builtin_amdgcn_mfma_f32_16x16x32_bf16(vh[dg], pbh, o_acc[qi][dg], 0, 0, 0);
        }
      }
    }
  }

  // ---- epilogue: x = O/l, direct global store in A-frag layout ----
#pragma unroll
  for (int qi = 0; qi < 2; ++qi) {
    float rl = 1.0f / l_r[qi];
    int m16 = b * 128 + qb * 8 + wv * 2 + qi;
#pragma unroll
    for (int dg = 0; dg < 4; ++dg) {
      float v0 = o_acc[qi][dg][0] * rl;
      float v1 = o_acc[qi][dg][1] * rl;
      float v2 = o_acc[qi][dg][2] * rl;
      float v3 = o_acc[qi][dg][3] * rl;
      ull_t hi, lo;
      qsplit4(v0, v1, v2, v3, hi, lo);
      size_t dst = (size_t)m16 * 16384 + (size_t)(h * 8 + dg * 2 + (l4 >> 1)) * 128 + l15 * 8 + (l4 & 1) * 4;
      *(ull_t*)(Xhi + dst) = hi;
      *(ull_t*)(Xlo + dst) = lo;
    }
  }
}

// ---------------------------------------------------------------------------
extern "C" void kernel_launch(void* const* d_in, const int* in_sizes, int n_in,
                              void* d_out, int out_size, void* d_ws,
                              size_t ws_size, hipStream_t stream) {
  (void)in_sizes; (void)n_in; (void)out_size; (void)ws_size;
  const float* query = (const float*)d_in[0];
  const float* key = (const float*)d_in[1];
  const float* value = (const float*)d_in[2];
  const int* mask = (const int*)d_in[3];
  const float* Wq = (const float*)d_in[4];
  const float* bq = (const float*)d_in[5];
  const float* Wk = (const float*)d_in[6];
  const float* bk = (const float*)d_in[7];
  const float* Wv = (const float*)d_in[8];
  const float* bv = (const float*)d_in[9];
  const float* Wo = (const float*)d_in[10];
  const float* bo = (const float*)d_in[11];
  float* out = (float*)d_out;

  // workspace layout (ushort elems). Total = 40 Mi elems = 80 MiB
  // (identical footprint to the round-2 PASSED layout; maskF aliases W0h,
  // which is dead after the Q-projection GEMM).
  const size_t EL = (size_t)MTOT * HID;  // 4 Mi elems
  const size_t WEL = (size_t)HID * HID;  // 1 Mi elems
  ushort_t* p = (ushort_t*)d_ws;
  ushort_t* X0h = p;            ushort_t* X0l = X0h + EL;
  ushort_t* X1h = X0l + EL;     ushort_t* X1l = X1h + EL;
  ushort_t* X2h = X1l + EL;     ushort_t* X2l = X2h + EL;
  ushort_t* W0h = X2l + EL;     ushort_t* W0l = W0h + WEL;
  ushort_t* W1h = W0l + WEL;    ushort_t* W1l = W1h + WEL;
  ushort_t* W2h = W1l + WEL;    ushort_t* W2l = W2h + WEL;
  ushort_t* W3h = W2l + WEL;    ushort_t* W3l = W3h + WEL;
  ushort_t* Qh = W3l + WEL;     ushort_t* Ql = Qh + EL;
  float* maskF = (float*)W0h;   // 16 KB, alias; valid only after Q-GEMM

  pack_mat<<<dim3(2048), dim3(256), 0, stream>>>(query, X0h, X0l, 0);
  pack_mat<<<dim3(2048), dim3(256), 0, stream>>>(key, X1h, X1l, 0);
  pack_mat<<<dim3(2048), dim3(256), 0, stream>>>(value, X2h, X2l, 0);
  pack_mat<<<dim3(512), dim3(256), 0, stream>>>(Wq, W0h, W0l, 1);
  pack_mat<<<dim3(512), dim3(256), 0, stream>>>(Wk, W1h, W1l, 1);
  pack_mat<<<dim3(512), dim3(256), 0, stream>>>(Wv, W2h, W2l, 1);
  pack_mat<<<dim3(512), dim3(256), 0, stream>>>(Wo, W3h, W3l, 1);

  gemm_pack<<<dim3(512), dim3(256), 0, stream>>>(X0h, X0l, W0h, W0l, bq, Qh, Ql,
                                                 nullptr, QSCALE, 0);  // Q
  // W0 (Wq packed) is dead from here; reuse its space for the float mask.
  mask_to_float<<<dim3(16), dim3(256), 0, stream>>>(mask, maskF);
  gemm_pack<<<dim3(512), dim3(256), 0, stream>>>(X1h, X1l, W1h, W1l, bk, X0h,
                                                 X0l, nullptr, 1.0f, 0);  // K
  gemm_pack<<<dim3(512), dim3(256), 0, stream>>>(X2h, X2l, W2h, W2l, bv, X1h,
                                                 X1l, nullptr, 1.0f, 1);  // V

  attn_kernel<<<dim3(512), dim3(256), 0, stream>>>(
      Qh, Ql, X0h, X0l, X1h, X1l, maskF, X2h, X2l);

  gemm_pack<<<dim3(512), dim3(256), 0, stream>>>(X2h, X2l, W3h, W3l, bo,
                                                 nullptr, nullptr, out, 1.0f,
                                                 2);
}